// Round 3
// baseline (1463.220 us; speedup 1.0000x reference)
//
#include <hip/hip_runtime.h>
#include <hip/hip_bf16.h>
#include <cstddef>
#include <cstdint>

// ---------- types ----------
typedef __bf16 bf16;
typedef bf16 bf16x8 __attribute__((ext_vector_type(8)));
typedef float f32x4 __attribute__((ext_vector_type(4)));

#define DEV static __device__ __forceinline__

DEV f32x4 mfma_bf16(bf16x8 a, bf16x8 b, f32x4 c) {
  return __builtin_amdgcn_mfma_f32_16x16x32_bf16(a, b, c, 0, 0, 0);
}

DEV float sigmoid_f(float x) { return 1.0f / (1.0f + __expf(-x)); }
DEV float tanh_f(float x) {
  float ax = fabsf(x);
  float e = __expf(-2.0f * ax);
  float t = 1.0f - 2.0f * e / (1.0f + e);
  return copysignf(t, x);
}

// fp8 e4m3 pack/unpack via gfx950 HW converts (self-consistent round-trip)
DEV uint32_t pack4_fp8(float a, float b, float c, float d) {
  int lo = __builtin_amdgcn_cvt_pk_fp8_f32(a, b, 0, false);
  return (uint32_t)__builtin_amdgcn_cvt_pk_fp8_f32(c, d, lo, true);
}

// ---------- problem constants ----------
// T=32, N=64, C=64, L=64, H=256, NA=16, NL=128
static constexpr int H_ = 256;

// ---------- canonical bf16 weight region: element offsets ----------
static constexpr int o_embed = 0;            // 32768
static constexpr int o_aemb = 32768;         // 4096
static constexpr int o_wi_f = 36864;         // 196608
static constexpr int o_wh_f = 233472;        // 196608
static constexpr int o_bi_f = 430080;        // 768
static constexpr int o_bh_f = 430848;        // 768
static constexpr int o_wi_b = 431616;        // 196608
static constexpr int o_wh_b = 628224;        // 196608
static constexpr int o_bi_b = 824832;        // 768
static constexpr int o_bh_b = 825600;        // 768
static constexpr int o_f_w1 = 826368;        // 81920
static constexpr int o_f_b1 = 908288;        // 256
static constexpr int o_f_w2 = 908544;        // 65536
static constexpr int o_f_b2 = 974080;        // 256
static constexpr int o_cell_wi = 974336;     // 196608
static constexpr int o_cell_wh = 1170944;    // 196608
static constexpr int o_cell_bi = 1367552;    // 768
static constexpr int o_cell_bh = 1368320;    // 768
static constexpr int o_critic_w = 1369088;   // 256
static constexpr int o_critic_b = 1369344;   // 1 (padded 16)
static constexpr int o_pointer_w = 1369360;  // 16384
static constexpr int o_pointer_b = 1385744;  // 64
static constexpr int o_actor_w = 1385808;    // 4096
static constexpr int o_actor_b = 1389904;    // 16
static constexpr int o_query_w = 1389920;    // 65536
static constexpr int o_query_b = 1455456;    // 256
static constexpr int CW_TOTAL = 1455712;     // elements

// ---------- workspace layout (bytes), total ~87 MB ----------
static constexpr size_t XI_OFF = 0;                               // bf16 [2][64 u][64 n][768]
static constexpr size_t XI_BYTES = 2ull * 64 * 64 * 768 * 2;      // 12,582,912
static constexpr size_t K1_OFF = XI_OFF + XI_BYTES;               // fp8 [64 n][32 slot][128 row][256]
static constexpr size_t K1_BYTES = 64ull * 32 * 128 * 256;        // 67,108,864
static constexpr size_t GI_OFF = K1_OFF + K1_BYTES;               // f32 [32][64][768]
static constexpr size_t GI_BYTES = 32ull * 64 * 768 * 4;          // 6,291,456
static constexpr size_t HD_OFF = GI_OFF + GI_BYTES;               // f32 [32][64][256]
static constexpr size_t HD_BYTES = 32ull * 64 * 256 * 4;          // 2,097,152
static constexpr size_t SLOT_OFF = HD_OFF + HD_BYTES;             // i32 [64 n][64 roll]
static constexpr size_t SLOT_BYTES = 64ull * 64 * 4;
static constexpr size_t FLG_OFF = SLOT_OFF + SLOT_BYTES;          // i32 [2]
static constexpr size_t FLG_BYTES = 256;
static constexpr size_t CW_OFF = FLG_OFF + FLG_BYTES;             // bf16 canonical weights

// =====================================================================
// D0: dtype detection. Samples low-16 bf16-exponent field of u32 words.
// bf16 storage -> ~97% of words have bits[14:7] in [96,130]; f32 -> ~14%.
// flags[0]: condition is f32. flags[1]: weights are f32.
// =====================================================================
__global__ void k_detect(const uint32_t* __restrict__ cond, const uint32_t* __restrict__ emb,
                         int* __restrict__ flags) {
  __shared__ int votes0[256], votes1[256];
  int tid = threadIdx.x;
  int c0 = 0, c1 = 0;
#pragma unroll
  for (int j = 0; j < 16; j++) {
    uint32_t wc = cond[tid * 16 + j];  // words [0,4096): 16 KB, safe either dtype
    uint32_t we = emb[tid * 16 + j];
    int ec = (int)((wc >> 7) & 0xFF);
    int ee = (int)((we >> 7) & 0xFF);
    c0 += (ec >= 96 && ec <= 130) ? 1 : 0;
    c1 += (ee >= 96 && ee <= 130) ? 1 : 0;
  }
  votes0[tid] = c0;
  votes1[tid] = c1;
  __syncthreads();
  if (tid == 0) {
    int s0 = 0, s1 = 0;
    for (int i = 0; i < 256; i++) { s0 += votes0[i]; s1 += votes1[i]; }
    flags[0] = (s0 < 2048) ? 1 : 0;
    flags[1] = (s1 < 2048) ? 1 : 0;
  }
}

// =====================================================================
// D0b: repack all float weight arrays into canonical bf16 region.
// =====================================================================
struct RepackArgs {
  const void* src[26];
  int off[26];
  int cnt[26];
};

__global__ void k_repack(RepackArgs args, const int* __restrict__ flags,
                         bf16* __restrict__ cw) {
  bool f32w = flags[1] != 0;
  int gidx = blockIdx.x * 2048 + threadIdx.x;
  for (int e = 0; e < 8; e++, gidx += 256) {
    int rem = gidx, s = 0;
    while (s < 26 && rem >= args.cnt[s]) { rem -= args.cnt[s]; s++; }
    if (s >= 26) return;  // gidx monotone -> later e also OOB
    float v = f32w ? ((const float*)args.src[s])[rem]
                   : (float)((const bf16*)args.src[s])[rem];
    cw[args.off[s] + rem] = (bf16)v;
  }
}

// =====================================================================
// S0: slot_map[n][roll] = compact slot id (first-occurrence order), or -1.
// At most 32 distinct rolls per n since T=32. grid <<<1,64>>>.
// =====================================================================
__global__ void k_slot(const int* __restrict__ p_idx, int* __restrict__ slot_map) {
  int n = threadIdx.x;  // 64 threads
  for (int r = 0; r < 64; r++) slot_map[n * 64 + r] = -1;
  int cnt = 0;
  for (int t = 0; t < 32; t++) {
    int p = p_idx[t * 64 + n];
    if (slot_map[n * 64 + p] < 0) slot_map[n * 64 + p] = cnt++;
  }
}

// =====================================================================
// B1: xi[d][u][n][g] = embed[lines[n][u]] @ wi_d^T + bi_d   (bf16 out)
// grid: 256 blocks (dir = bx&1, rb = bx>>1 over 128 row-blocks of 32), 256 thr
// =====================================================================
__global__ __launch_bounds__(256, 2)
void k_xi(const int* __restrict__ lines, const bf16* __restrict__ cw,
          bf16* __restrict__ xi) {
  int bx = blockIdx.x;
  int dir = bx & 1, rb = bx >> 1;
  const bf16* embed = cw + o_embed;
  const bf16* wi = cw + (dir ? o_wi_b : o_wi_f);
  const bf16* bi = cw + (dir ? o_bi_b : o_bi_f);
  int tid = threadIdx.x;
  int w = tid >> 6, l = tid & 63, quad = l >> 4, l15 = l & 15;

  __shared__ __attribute__((aligned(16))) bf16 xs[32 * 264];

  { // stage 32 gathered embed rows
    int row = tid >> 3;
    int seg = tid & 7;
    int grow = rb * 32 + row;          // grow = u*64 + n
    int u = grow >> 6, n = grow & 63;
    int line = lines[n * 64 + u];
    const bf16* src = embed + (size_t)line * H_ + seg * 32;
    bf16* dst = xs + row * 264 + seg * 32;
#pragma unroll
    for (int e = 0; e < 4; e++)
      *(bf16x8*)(dst + e * 8) = *(const bf16x8*)(src + e * 8);
  }
  __syncthreads();

  f32x4 acc[2][12];
#pragma unroll
  for (int mt = 0; mt < 2; mt++)
#pragma unroll
    for (int nt = 0; nt < 12; nt++) acc[mt][nt] = f32x4{0.f, 0.f, 0.f, 0.f};

#pragma unroll
  for (int ks = 0; ks < 8; ks++) {
    int koff = ks * 32 + quad * 8;
    bf16x8 a0 = *(const bf16x8*)(xs + l15 * 264 + koff);
    bf16x8 a1 = *(const bf16x8*)(xs + (l15 + 16) * 264 + koff);
#pragma unroll
    for (int nt = 0; nt < 12; nt++) {
      int g = (w * 12 + nt) * 16 + l15;
      bf16x8 b = *(const bf16x8*)(wi + (size_t)g * H_ + koff);
      acc[0][nt] = mfma_bf16(a0, b, acc[0][nt]);
      acc[1][nt] = mfma_bf16(a1, b, acc[1][nt]);
    }
  }

  size_t base = (size_t)dir * 4096 * 768;
#pragma unroll
  for (int nt = 0; nt < 12; nt++) {
    int g = (w * 12 + nt) * 16 + l15;
    float bias = (float)bi[g];
#pragma unroll
    for (int mt = 0; mt < 2; mt++)
#pragma unroll
      for (int r = 0; r < 4; r++) {
        int m = mt * 16 + quad * 4 + r;
        int grow = rb * 32 + m;
        xi[base + (size_t)grow * 768 + g] = (bf16)(acc[mt][nt][r] + bias);
      }
  }
}

// =====================================================================
// B2: BiGRU over all rolls. grid: 256 WGs (dir=bx&1, nchunk=(bx>>1)&1,
// roll=bx>>2), 512 threads (8 waves). Each WG: 32 batch rows, 64 steps.
// Wave w owns hidden cols [w*32, w*32+32). Writes fp8 compact K1c.
// =====================================================================
__global__ __launch_bounds__(512, 2)
void k_bigru(const bf16* __restrict__ cw, const bf16* __restrict__ xi,
             const int* __restrict__ slot_map, unsigned char* __restrict__ K1c) {
  int bx = blockIdx.x;
  int dir = bx & 1, nchunk = (bx >> 1) & 1, roll = bx >> 2;
  const bf16* wh = cw + (dir ? o_wh_b : o_wh_f);
  const bf16* bh = cw + (dir ? o_bh_b : o_bh_f);
  int tid = threadIdx.x;
  int w = tid >> 6, l = tid & 63, quad = l >> 4, l15 = l & 15;
  int cbase = w * 32;

  __shared__ __attribute__((aligned(16))) bf16 hbuf[32 * 264];
  for (int idx = tid; idx < 32 * 264; idx += 512) hbuf[idx] = (bf16)0.f;

  // per-thread copy-phase constants
  int n_copy = nchunk * 32 + (tid >> 4);
  int kslot = slot_map[n_copy * 64 + roll];  // -1 if this (n, roll) never used
  unsigned char* dst_base =
      K1c + ((size_t)n_copy * 32 + (kslot < 0 ? 0 : kslot)) * 32768 + (tid & 15) * 16;

  float hreg[2][2][4];
#pragma unroll
  for (int mt = 0; mt < 2; mt++)
#pragma unroll
    for (int c2 = 0; c2 < 2; c2++)
#pragma unroll
      for (int r = 0; r < 4; r++) hreg[mt][c2][r] = 0.f;

  float bhv[3][2];
  const bf16* bp[3][2];
#pragma unroll
  for (int g = 0; g < 3; g++)
#pragma unroll
    for (int c2 = 0; c2 < 2; c2++) {
      int grow = g * 256 + cbase + c2 * 16 + l15;
      bhv[g][c2] = (float)bh[grow];
      bp[g][c2] = wh + (size_t)grow * 256 + quad * 8;
    }

  const bf16* xibase = xi + (size_t)dir * 4096 * 768;
  __syncthreads();

  for (int t = 0; t < 64; t++) {
    int u = (dir == 0) ? ((t - roll) & 63) : ((63 - t - roll) & 63);
    int j = (dir == 0) ? t : 63 - t;

    // gh = h_{t-1} @ wh^T
    f32x4 acc[2][3][2];
#pragma unroll
    for (int mt = 0; mt < 2; mt++)
#pragma unroll
      for (int g = 0; g < 3; g++)
#pragma unroll
        for (int c2 = 0; c2 < 2; c2++) acc[mt][g][c2] = f32x4{0.f, 0.f, 0.f, 0.f};

#pragma unroll
    for (int ks = 0; ks < 8; ks++) {
      int koff = ks * 32 + quad * 8;
      bf16x8 a0 = *(const bf16x8*)(hbuf + l15 * 264 + koff);
      bf16x8 a1 = *(const bf16x8*)(hbuf + (l15 + 16) * 264 + koff);
#pragma unroll
      for (int g = 0; g < 3; g++)
#pragma unroll
        for (int c2 = 0; c2 < 2; c2++) {
          bf16x8 b = *(const bf16x8*)(bp[g][c2] + ks * 32);
          acc[0][g][c2] = mfma_bf16(a0, b, acc[0][g][c2]);
          acc[1][g][c2] = mfma_bf16(a1, b, acc[1][g][c2]);
        }
    }

    // gates (per-lane; lane owns (m, c) cells of its wave's 32 cols)
#pragma unroll
    for (int mt = 0; mt < 2; mt++)
#pragma unroll
      for (int c2 = 0; c2 < 2; c2++) {
        int c = cbase + c2 * 16 + l15;
#pragma unroll
        for (int r = 0; r < 4; r++) {
          int m = mt * 16 + quad * 4 + r;
          int n_g = nchunk * 32 + m;
          const bf16* xr = xibase + ((size_t)u * 64 + n_g) * 768;
          float ir = (float)xr[c];
          float iz = (float)xr[256 + c];
          float inn = (float)xr[512 + c];
          float hr = acc[mt][0][c2][r] + bhv[0][c2];
          float hz = acc[mt][1][c2][r] + bhv[1][c2];
          float hn = acc[mt][2][c2][r] + bhv[2][c2];
          float rg = sigmoid_f(ir + hr);
          float zg = sigmoid_f(iz + hz);
          float ng = tanh_f(inn + rg * hn);
          hreg[mt][c2][r] = (1.f - zg) * ng + zg * hreg[mt][c2][r];
        }
      }

    __syncthreads();  // everyone done reading old hbuf
#pragma unroll
    for (int mt = 0; mt < 2; mt++)
#pragma unroll
      for (int c2 = 0; c2 < 2; c2++) {
        int c = cbase + c2 * 16 + l15;
#pragma unroll
        for (int r = 0; r < 4; r++) {
          int m = mt * 16 + quad * 4 + r;
          hbuf[m * 264 + c] = (bf16)hreg[mt][c2][r];
        }
      }
    __syncthreads();  // new hbuf visible

    // fp8-encode + store hbuf row -> K1c[n][slot] row (j*2+dir), if needed
    if (kslot >= 0) {
      int n_m = tid >> 4;
      int col = (tid & 15) * 16;  // element offset (== byte offset in fp8)
      bf16x8 v0 = *(const bf16x8*)(hbuf + n_m * 264 + col);
      bf16x8 v1 = *(const bf16x8*)(hbuf + n_m * 264 + col + 8);
      uint32_t wds[4];
      wds[0] = pack4_fp8((float)v0[0], (float)v0[1], (float)v0[2], (float)v0[3]);
      wds[1] = pack4_fp8((float)v0[4], (float)v0[5], (float)v0[6], (float)v0[7]);
      wds[2] = pack4_fp8((float)v1[0], (float)v1[1], (float)v1[2], (float)v1[3]);
      wds[3] = pack4_fp8((float)v1[4], (float)v1[5], (float)v1[6], (float)v1[7]);
      uint32_t* dst = (uint32_t*)(dst_base + (size_t)(j * 2 + dir) * 256);
      dst[0] = wds[0]; dst[1] = wds[1]; dst[2] = wds[2]; dst[3] = wds[3];
    }
  }
}

// =====================================================================
// D1: gi[t][n][:] = cell_wi @ relu(f_w2 @ relu(f_w1 @ obs + b1) + b2) + cell_bi
// grid: 64 WGs (32 rows each, row = t*64+n), 256 threads
// =====================================================================
__global__ __launch_bounds__(256, 2)
void k_dec_gi(const void* __restrict__ cond_raw, const int* __restrict__ flags,
              const int* __restrict__ a_idx, const bf16* __restrict__ cw,
              float* __restrict__ gi) {
  int rb = blockIdx.x;
  int tid = threadIdx.x;
  int w = tid >> 6, l = tid & 63, quad = l >> 4, l15 = l & 15;
  const bf16* aemb = cw + o_aemb;
  const bf16* f_w1 = cw + o_f_w1;
  const bf16* f_b1 = cw + o_f_b1;
  const bf16* f_w2 = cw + o_f_w2;
  const bf16* f_b2 = cw + o_f_b2;
  const bf16* cell_wi = cw + o_cell_wi;
  const bf16* cell_bi = cw + o_cell_bi;
  bool cf32 = flags[0] != 0;

  __shared__ __attribute__((aligned(16))) bf16 obs[32 * 328];
  __shared__ __attribute__((aligned(16))) bf16 xf1[32 * 264];

  for (int e = tid; e < 32 * 320; e += 256) {
    int row = e / 320, col = e - row * 320;
    int grow = rb * 32 + row;
    int t = grow >> 6, n = grow & 63;
    float v;
    if (col < 64) {
      v = cf32 ? ((const float*)cond_raw)[(size_t)grow * 64 + col]
               : (float)((const bf16*)cond_raw)[(size_t)grow * 64 + col];
    } else {
      int ap = (t == 0) ? 0 : a_idx[(t - 1) * 64 + n];
      v = (float)aemb[ap * 256 + (col - 64)];
    }
    obs[row * 328 + col] = (bf16)v;
  }
  __syncthreads();

  { // GEMM1: K=320 -> relu -> xf1
    f32x4 acc[2][4];
#pragma unroll
    for (int mt = 0; mt < 2; mt++)
#pragma unroll
      for (int nt = 0; nt < 4; nt++) acc[mt][nt] = f32x4{0.f, 0.f, 0.f, 0.f};
#pragma unroll
    for (int ks = 0; ks < 10; ks++) {
      int koff = ks * 32 + quad * 8;
      bf16x8 a0 = *(const bf16x8*)(obs + l15 * 328 + koff);
      bf16x8 a1 = *(const bf16x8*)(obs + (l15 + 16) * 328 + koff);
#pragma unroll
      for (int nt = 0; nt < 4; nt++) {
        int g = (w * 4 + nt) * 16 + l15;
        bf16x8 b = *(const bf16x8*)(f_w1 + (size_t)g * 320 + koff);
        acc[0][nt] = mfma_bf16(a0, b, acc[0][nt]);
        acc[1][nt] = mfma_bf16(a1, b, acc[1][nt]);
      }
    }
#pragma unroll
    for (int nt = 0; nt < 4; nt++) {
      int g = (w * 4 + nt) * 16 + l15;
      float bias = (float)f_b1[g];
#pragma unroll
      for (int mt = 0; mt < 2; mt++)
#pragma unroll
        for (int r = 0; r < 4; r++) {
          int m = mt * 16 + quad * 4 + r;
          xf1[m * 264 + g] = (bf16)fmaxf(acc[mt][nt][r] + bias, 0.f);
        }
    }
  }
  __syncthreads();

  bf16* xf2 = obs;  // reuse (stride 264)
  { // GEMM2: K=256 -> relu -> xf2
    f32x4 acc[2][4];
#pragma unroll
    for (int mt = 0; mt < 2; mt++)
#pragma unroll
      for (int nt = 0; nt < 4; nt++) acc[mt][nt] = f32x4{0.f, 0.f, 0.f, 0.f};
#pragma unroll
    for (int ks = 0; ks < 8; ks++) {
      int koff = ks * 32 + quad * 8;
      bf16x8 a0 = *(const bf16x8*)(xf1 + l15 * 264 + koff);
      bf16x8 a1 = *(const bf16x8*)(xf1 + (l15 + 16) * 264 + koff);
#pragma unroll
      for (int nt = 0; nt < 4; nt++) {
        int g = (w * 4 + nt) * 16 + l15;
        bf16x8 b = *(const bf16x8*)(f_w2 + (size_t)g * 256 + koff);
        acc[0][nt] = mfma_bf16(a0, b, acc[0][nt]);
        acc[1][nt] = mfma_bf16(a1, b, acc[1][nt]);
      }
    }
#pragma unroll
    for (int nt = 0; nt < 4; nt++) {
      int g = (w * 4 + nt) * 16 + l15;
      float bias = (float)f_b2[g];
#pragma unroll
      for (int mt = 0; mt < 2; mt++)
#pragma unroll
        for (int r = 0; r < 4; r++) {
          int m = mt * 16 + quad * 4 + r;
          xf2[m * 264 + g] = (bf16)fmaxf(acc[mt][nt][r] + bias, 0.f);
        }
    }
  }
  __syncthreads();

  { // GEMM3: -> gi (f32, global)
    f32x4 acc[2][12];
#pragma unroll
    for (int mt = 0; mt < 2; mt++)
#pragma unroll
      for (int nt = 0; nt < 12; nt++) acc[mt][nt] = f32x4{0.f, 0.f, 0.f, 0.f};
#pragma unroll
    for (int ks = 0; ks < 8; ks++) {
      int koff = ks * 32 + quad * 8;
      bf16x8 a0 = *(const bf16x8*)(xf2 + l15 * 264 + koff);
      bf16x8 a1 = *(const bf16x8*)(xf2 + (l15 + 16) * 264 + koff);
#pragma unroll
      for (int nt = 0; nt < 12; nt++) {
        int g = (w * 12 + nt) * 16 + l15;
        bf16x8 b = *(const bf16x8*)(cell_wi + (size_t)g * 256 + koff);
        acc[0][nt] = mfma_bf16(a0, b, acc[0][nt]);
        acc[1][nt] = mfma_bf16(a1, b, acc[1][nt]);
      }
    }
#pragma unroll
    for (int nt = 0; nt < 12; nt++) {
      int g = (w * 12 + nt) * 16 + l15;
      float bias = (float)cell_bi[g];
#pragma unroll
      for (int mt = 0; mt < 2; mt++)
#pragma unroll
        for (int r = 0; r < 4; r++) {
          int m = mt * 16 + quad * 4 + r;
          int grow = rb * 32 + m;
          gi[(size_t)grow * 768 + g] = acc[mt][nt][r] + bias;
        }
    }
  }
}

// =====================================================================
// D2: decoder GRU-cell recurrence, independent per n. grid 64 WGs, 256 thr.
// thread c handles gate columns {c, 256+c, 512+c}.
// =====================================================================
__global__ void k_dec_h(const bf16* __restrict__ cw,
                        const float* __restrict__ gi, float* __restrict__ hdec) {
  int n = blockIdx.x;
  int c = threadIdx.x;
  const bf16* cell_wh = cw + o_cell_wh;
  const bf16* cell_bh = cw + o_cell_bh;
  __shared__ float hs[256];
  hs[c] = 0.f;
  __syncthreads();
  float bhr = (float)cell_bh[c];
  float bhz = (float)cell_bh[256 + c];
  float bhn = (float)cell_bh[512 + c];
  const bf16* wr = cell_wh + (size_t)c * 256;
  const bf16* wz = cell_wh + (size_t)(256 + c) * 256;
  const bf16* wn = cell_wh + (size_t)(512 + c) * 256;
  for (int t = 0; t < 32; t++) {
    float hr = bhr, hz = bhz, hn = bhn;
#pragma unroll 4
    for (int k0 = 0; k0 < 256; k0 += 8) {
      bf16x8 wrv = *(const bf16x8*)(wr + k0);
      bf16x8 wzv = *(const bf16x8*)(wz + k0);
      bf16x8 wnv = *(const bf16x8*)(wn + k0);
#pragma unroll
      for (int e = 0; e < 8; e++) {
        float hv = hs[k0 + e];
        hr += (float)wrv[e] * hv;
        hz += (float)wzv[e] * hv;
        hn += (float)wnv[e] * hv;
      }
    }
    const float* gr = gi + ((size_t)t * 64 + n) * 768;
    float rg = sigmoid_f(gr[c] + hr);
    float zg = sigmoid_f(gr[256 + c] + hz);
    float ng = tanh_f(gr[512 + c] + rg * hn);
    float hnew = (1.f - zg) * ng + zg * hs[c];
    __syncthreads();
    hs[c] = hnew;
    hdec[((size_t)t * 64 + n) * 256 + c] = hnew;
    __syncthreads();
  }
}

// =====================================================================
// D3: heads + attention + output packing. grid 2048 WGs (t*64+n), 256 thr.
// out row: [a, p, v, h(256), a_probs(16), p_probs(64)] = 339 elems.
// Output dtype: bf16 unless flags[1] (all-f32 world) -> f32.
// =====================================================================
__global__ void k_dec_out(const float* __restrict__ hdec, const unsigned char* __restrict__ K1c,
                          const int* __restrict__ slot_map, const int* __restrict__ flags,
                          const int* __restrict__ a_idx, const int* __restrict__ p_idx,
                          const bf16* __restrict__ cw, void* __restrict__ out_raw) {
  int bx = blockIdx.x;
  int t = bx >> 6, n = bx & 63;
  int tid = threadIdx.x;
  int w = tid >> 6, l = tid & 63;
  const bf16* critic_w = cw + o_critic_w;
  const bf16* critic_b = cw + o_critic_b;
  const bf16* pointer_w = cw + o_pointer_w;
  const bf16* pointer_b = cw + o_pointer_b;
  const bf16* actor_w = cw + o_actor_w;
  const bf16* actor_b = cw + o_actor_b;
  const bf16* query_w = cw + o_query_w;
  const bf16* query_b = cw + o_query_b;

  __shared__ float hs[256], qs[256], ls[256], sA[256];
  __shared__ float pl[64], al[16], red[8], scal[4];
  __shared__ __attribute__((aligned(16))) unsigned char ksb[128 * 264];  // fp8 rows, stride 264 B

  hs[tid] = hdec[((size_t)t * 64 + n) * 256 + tid];
  int p = p_idx[t * 64 + n];
  int slot = slot_map[n * 64 + p];  // guaranteed >= 0
  {
    const uint32_t* kg = (const uint32_t*)(K1c + ((size_t)n * 32 + slot) * 32768);
#pragma unroll
    for (int e = 0; e < 8; e++) {
      int flat = (e * 256 + tid) * 16;  // byte offset into 32768-B slice
      int kk = flat >> 8, col = flat & 255;
      uint32_t w0 = kg[(flat >> 2) + 0], w1 = kg[(flat >> 2) + 1];
      uint32_t w2 = kg[(flat >> 2) + 2], w3 = kg[(flat >> 2) + 3];
      uint32_t* d0 = (uint32_t*)(ksb + kk * 264 + col);
      d0[0] = w0; d0[1] = w1; d0[2] = w2; d0[3] = w3;
    }
  }
  __syncthreads();

  { // q = h @ query_w^T + query_b
    float acc = (float)query_b[tid];
    const bf16* qw = query_w + (size_t)tid * 256;
#pragma unroll 4
    for (int k0 = 0; k0 < 256; k0 += 8) {
      bf16x8 wv = *(const bf16x8*)(qw + k0);
#pragma unroll
      for (int e = 0; e < 8; e++) acc += (float)wv[e] * hs[k0 + e];
    }
    qs[tid] = acc;
  }
  { // v partials (wave reduce)
    float vp = hs[tid] * (float)critic_w[tid];
#pragma unroll
    for (int s = 32; s > 0; s >>= 1) vp += __shfl_down(vp, s, 64);
    if (l == 0) red[w] = vp;
  }
  { // pointer-logit partials: (pp = tid>>2, e = tid&3)
    int pp = tid >> 2, e = tid & 3;
    const bf16* pw = pointer_w + (size_t)pp * 256 + e * 64;
    float acc = 0.f;
#pragma unroll 8
    for (int hh = 0; hh < 64; hh++) acc += (float)pw[hh] * hs[e * 64 + hh];
    ls[tid] = acc;
  }
  __syncthreads();

  if (tid < 64) {  // fold + softmax over 64 (wave0)
    float lg = ls[tid * 4] + ls[tid * 4 + 1] + ls[tid * 4 + 2] + ls[tid * 4 + 3] +
               (float)pointer_b[tid];
    float mx = lg;
#pragma unroll
    for (int m = 32; m > 0; m >>= 1) mx = fmaxf(mx, __shfl_xor(mx, m, 64));
    float ex = __expf(lg - mx);
    float sm = ex;
#pragma unroll
    for (int m = 32; m > 0; m >>= 1) sm += __shfl_xor(sm, m, 64);
    pl[tid] = ex / sm;
  }
  if (tid == 0) scal[0] = red[0] + red[1] + red[2] + red[3] + (float)critic_b[0];
  __syncthreads();

  { // l partials: (kk = tid&127, hc = tid>>7)
    int kk = tid & 127, hc = tid >> 7;
    const uint32_t* kr = (const uint32_t*)(ksb + kk * 264 + hc * 128);
    const float* qr = qs + hc * 128;
    float acc = 0.f;
#pragma unroll 8
    for (int u = 0; u < 32; u++) {
      uint32_t b4 = kr[u];
      acc += __builtin_amdgcn_cvt_f32_fp8(b4, 0) * qr[u * 4 + 0];
      acc += __builtin_amdgcn_cvt_f32_fp8(b4, 1) * qr[u * 4 + 1];
      acc += __builtin_amdgcn_cvt_f32_fp8(b4, 2) * qr[u * 4 + 2];
      acc += __builtin_amdgcn_cvt_f32_fp8(b4, 3) * qr[u * 4 + 3];
    }
    ls[tid] = acc;
  }
  __syncthreads();
  if (tid < 128) ls[tid] += ls[tid + 128];
  __syncthreads();

  float zzv;
  { // zz[c] = sum_kk l[kk] * k[kk][c]
    const unsigned char* kc = ksb + (tid & ~3);
    int sh = (tid & 3) * 8;
    float acc = 0.f;
#pragma unroll 8
    for (int kk = 0; kk < 128; kk++) {
      uint32_t d = *(const uint32_t*)(kc + kk * 264);
      acc += ls[kk] * __builtin_amdgcn_cvt_f32_fp8((int)(d >> sh), 0);
    }
    zzv = acc;
  }
  __syncthreads();
  qs[tid] = zzv;  // reuse qs as zz
  __syncthreads();

  { // actor-logit partials: (a = tid>>4, e = tid&15)
    int a = tid >> 4, e = tid & 15;
    const bf16* aw = actor_w + (size_t)a * 256 + e * 16;
    const float* zr = qs + e * 16;
    float acc = 0.f;
#pragma unroll
    for (int hh = 0; hh < 16; hh++) acc += (float)aw[hh] * zr[hh];
    sA[tid] = acc;
  }
  __syncthreads();
  if (tid < 16) {
    float lg = (float)actor_b[tid];
#pragma unroll
    for (int e = 0; e < 16; e++) lg += sA[tid * 16 + e];
    float mx = lg;
#pragma unroll
    for (int m = 8; m > 0; m >>= 1) mx = fmaxf(mx, __shfl_xor(mx, m, 16));
    float ex = __expf(lg - mx);
    float sm = ex;
#pragma unroll
    for (int m = 8; m > 0; m >>= 1) sm += __shfl_xor(sm, m, 16);
    al[tid] = ex / sm;
  }
  __syncthreads();

  size_t rowoff = (size_t)(t * 64 + n) * 339;
  if (flags[1]) {  // all-f32 world: f32 output
    float* ob = (float*)out_raw + rowoff;
    if (tid == 0) {
      ob[0] = (float)a_idx[t * 64 + n];
      ob[1] = (float)p;
      ob[2] = scal[0];
    }
    ob[3 + tid] = hs[tid];
    if (tid < 16) ob[259 + tid] = al[tid];
    if (tid < 64) ob[275 + tid] = pl[tid];
  } else {  // bf16 output
    bf16* ob = (bf16*)out_raw + rowoff;
    if (tid == 0) {
      ob[0] = (bf16)(float)a_idx[t * 64 + n];
      ob[1] = (bf16)(float)p;
      ob[2] = (bf16)scal[0];
    }
    ob[3 + tid] = (bf16)hs[tid];
    if (tid < 16) ob[259 + tid] = (bf16)al[tid];
    if (tid < 64) ob[275 + tid] = (bf16)pl[tid];
  }
}

// =====================================================================
extern "C" void kernel_launch(void* const* d_in, const int* in_sizes, int n_in,
                              void* d_out, int out_size, void* d_ws, size_t ws_size,
                              hipStream_t stream) {
  (void)in_sizes; (void)n_in; (void)out_size; (void)ws_size;
  const void* condition = d_in[0];
  const int* lines      = (const int*)d_in[1];
  const int* a_idx      = (const int*)d_in[2];
  const int* p_idx      = (const int*)d_in[3];

  char* ws = (char*)d_ws;
  bf16* xi            = (bf16*)(ws + XI_OFF);
  unsigned char* K1c  = (unsigned char*)(ws + K1_OFF);
  float* gi           = (float*)(ws + GI_OFF);
  float* hdec         = (float*)(ws + HD_OFF);
  int* slot_map       = (int*)(ws + SLOT_OFF);
  int* flags          = (int*)(ws + FLG_OFF);
  bf16* cw            = (bf16*)(ws + CW_OFF);

  // repack table: d_in index, canonical offset, element count
  static const int src_idx[26] = {4, 5, 6, 7, 8, 9, 10, 11, 12, 13, 14, 15, 16,
                                  17, 18, 19, 20, 21, 22, 23, 24, 25, 26, 27, 28, 29};
  static const int offs[26] = {o_embed, o_aemb, o_wi_f, o_wh_f, o_bi_f, o_bh_f,
                               o_wi_b, o_wh_b, o_bi_b, o_bh_b, o_f_w1, o_f_b1,
                               o_f_w2, o_f_b2, o_cell_wi, o_cell_wh, o_cell_bi,
                               o_cell_bh, o_critic_w, o_critic_b, o_pointer_w,
                               o_pointer_b, o_actor_w, o_actor_b, o_query_w, o_query_b};
  static const int cnts[26] = {32768, 4096, 196608, 196608, 768, 768,
                               196608, 196608, 768, 768, 81920, 256,
                               65536, 256, 196608, 196608, 768,
                               768, 256, 1, 16384, 64, 4096, 16, 65536, 256};
  RepackArgs ra;
  int total = 0;
  for (int i = 0; i < 26; i++) {
    ra.src[i] = d_in[src_idx[i]];
    ra.off[i] = offs[i];
    ra.cnt[i] = cnts[i];
    total += cnts[i];
  }
  int nchunks = (total + 2047) / 2048;

  k_detect<<<1, 256, 0, stream>>>((const uint32_t*)condition, (const uint32_t*)d_in[4], flags);
  k_repack<<<nchunks, 256, 0, stream>>>(ra, flags, cw);
  k_slot<<<1, 64, 0, stream>>>(p_idx, slot_map);
  k_xi<<<256, 256, 0, stream>>>(lines, cw, xi);
  k_bigru<<<256, 512, 0, stream>>>(cw, xi, slot_map, K1c);
  k_dec_gi<<<64, 256, 0, stream>>>(condition, flags, a_idx, cw, gi);
  k_dec_h<<<64, 256, 0, stream>>>(cw, gi, hdec);
  k_dec_out<<<2048, 256, 0, stream>>>(hdec, K1c, slot_map, flags, a_idx, p_idx, cw, d_out);
}

// Round 4
// 1186.286 us; speedup vs baseline: 1.2334x; 1.2334x over previous
//
#include <hip/hip_runtime.h>
#include <hip/hip_bf16.h>
#include <cstddef>
#include <cstdint>

// ---------- types ----------
typedef __bf16 bf16;
typedef bf16 bf16x8 __attribute__((ext_vector_type(8)));
typedef float f32x4 __attribute__((ext_vector_type(4)));

#define DEV static __device__ __forceinline__

DEV f32x4 mfma_bf16(bf16x8 a, bf16x8 b, f32x4 c) {
  return __builtin_amdgcn_mfma_f32_16x16x32_bf16(a, b, c, 0, 0, 0);
}

DEV float sigmoid_f(float x) { return 1.0f / (1.0f + __expf(-x)); }
DEV float tanh_f(float x) {
  float ax = fabsf(x);
  float e = __expf(-2.0f * ax);
  float t = 1.0f - 2.0f * e / (1.0f + e);
  return copysignf(t, x);
}

// fp8 e4m3 pack/unpack via gfx950 HW converts (self-consistent round-trip)
DEV uint32_t pack4_fp8(float a, float b, float c, float d) {
  int lo = __builtin_amdgcn_cvt_pk_fp8_f32(a, b, 0, false);
  return (uint32_t)__builtin_amdgcn_cvt_pk_fp8_f32(c, d, lo, true);
}

// ---------- problem constants ----------
// T=32, N=64, C=64, L=64, H=256, NA=16, NL=128
static constexpr int H_ = 256;

// ---------- canonical bf16 weight region: element offsets ----------
static constexpr int o_embed = 0;            // 32768
static constexpr int o_aemb = 32768;         // 4096
static constexpr int o_wi_f = 36864;         // 196608
static constexpr int o_wh_f = 233472;        // 196608
static constexpr int o_bi_f = 430080;        // 768
static constexpr int o_bh_f = 430848;        // 768
static constexpr int o_wi_b = 431616;        // 196608
static constexpr int o_wh_b = 628224;        // 196608
static constexpr int o_bi_b = 824832;        // 768
static constexpr int o_bh_b = 825600;        // 768
static constexpr int o_f_w1 = 826368;        // 81920
static constexpr int o_f_b1 = 908288;        // 256
static constexpr int o_f_w2 = 908544;        // 65536
static constexpr int o_f_b2 = 974080;        // 256
static constexpr int o_cell_wi = 974336;     // 196608
static constexpr int o_cell_wh = 1170944;    // 196608
static constexpr int o_cell_bi = 1367552;    // 768
static constexpr int o_cell_bh = 1368320;    // 768
static constexpr int o_critic_w = 1369088;   // 256
static constexpr int o_critic_b = 1369344;   // 1 (padded 16)
static constexpr int o_pointer_w = 1369360;  // 16384
static constexpr int o_pointer_b = 1385744;  // 64
static constexpr int o_actor_w = 1385808;    // 4096
static constexpr int o_actor_b = 1389904;    // 16
static constexpr int o_query_w = 1389920;    // 65536
static constexpr int o_query_b = 1455456;    // 256

// ---------- workspace layout (bytes), total ~87 MB ----------
static constexpr size_t XI_OFF = 0;                               // bf16 [2][64 u][64 n][768]
static constexpr size_t XI_BYTES = 2ull * 64 * 64 * 768 * 2;      // 12,582,912
static constexpr size_t K1_OFF = XI_OFF + XI_BYTES;               // fp8 [64 n][32 slot][128 row][256]
static constexpr size_t K1_BYTES = 64ull * 32 * 128 * 256;        // 67,108,864
static constexpr size_t GI_OFF = K1_OFF + K1_BYTES;               // f32 [32][64][768]
static constexpr size_t GI_BYTES = 32ull * 64 * 768 * 4;          // 6,291,456
static constexpr size_t HD_OFF = GI_OFF + GI_BYTES;               // f32 [32][64][256]
static constexpr size_t HD_BYTES = 32ull * 64 * 256 * 4;          // 2,097,152
static constexpr size_t SLOT_OFF = HD_OFF + HD_BYTES;             // i32 [64 n][64 roll]
static constexpr size_t SLOT_BYTES = 64ull * 64 * 4;
static constexpr size_t FLG_OFF = SLOT_OFF + SLOT_BYTES;          // i32 [2]
static constexpr size_t FLG_BYTES = 256;
static constexpr size_t CW_OFF = FLG_OFF + FLG_BYTES;             // bf16 canonical weights

// =====================================================================
// D0: dtype detection (bf16 vs f32 storage).
// =====================================================================
__global__ void k_detect(const uint32_t* __restrict__ cond, const uint32_t* __restrict__ emb,
                         int* __restrict__ flags) {
  __shared__ int votes0[256], votes1[256];
  int tid = threadIdx.x;
  int c0 = 0, c1 = 0;
#pragma unroll
  for (int j = 0; j < 16; j++) {
    uint32_t wc = cond[tid * 16 + j];
    uint32_t we = emb[tid * 16 + j];
    int ec = (int)((wc >> 7) & 0xFF);
    int ee = (int)((we >> 7) & 0xFF);
    c0 += (ec >= 96 && ec <= 130) ? 1 : 0;
    c1 += (ee >= 96 && ee <= 130) ? 1 : 0;
  }
  votes0[tid] = c0;
  votes1[tid] = c1;
  __syncthreads();
  if (tid == 0) {
    int s0 = 0, s1 = 0;
    for (int i = 0; i < 256; i++) { s0 += votes0[i]; s1 += votes1[i]; }
    flags[0] = (s0 < 2048) ? 1 : 0;
    flags[1] = (s1 < 2048) ? 1 : 0;
  }
}

// =====================================================================
// D0b: repack all float weight arrays into canonical bf16 region.
// =====================================================================
struct RepackArgs {
  const void* src[26];
  int off[26];
  int cnt[26];
};

__global__ void k_repack(RepackArgs args, const int* __restrict__ flags,
                         bf16* __restrict__ cw) {
  bool f32w = flags[1] != 0;
  int gidx = blockIdx.x * 2048 + threadIdx.x;
  for (int e = 0; e < 8; e++, gidx += 256) {
    int rem = gidx, s = 0;
    while (s < 26 && rem >= args.cnt[s]) { rem -= args.cnt[s]; s++; }
    if (s >= 26) return;
    float v = f32w ? ((const float*)args.src[s])[rem]
                   : (float)((const bf16*)args.src[s])[rem];
    cw[args.off[s] + rem] = (bf16)v;
  }
}

// =====================================================================
// S0: slot_map[n][roll] = compact slot id or -1.
// =====================================================================
__global__ void k_slot(const int* __restrict__ p_idx, int* __restrict__ slot_map) {
  int n = threadIdx.x;  // 64 threads
  for (int r = 0; r < 64; r++) slot_map[n * 64 + r] = -1;
  int cnt = 0;
  for (int t = 0; t < 32; t++) {
    int p = p_idx[t * 64 + n];
    if (slot_map[n * 64 + p] < 0) slot_map[n * 64 + p] = cnt++;
  }
}

// =====================================================================
// B1: xi[d][u][n][g] = embed[lines[n][u]] @ wi_d^T + bi_d   (bf16 out)
// =====================================================================
__global__ __launch_bounds__(256, 2)
void k_xi(const int* __restrict__ lines, const bf16* __restrict__ cw,
          bf16* __restrict__ xi) {
  int bx = blockIdx.x;
  int dir = bx & 1, rb = bx >> 1;
  const bf16* embed = cw + o_embed;
  const bf16* wi = cw + (dir ? o_wi_b : o_wi_f);
  const bf16* bi = cw + (dir ? o_bi_b : o_bi_f);
  int tid = threadIdx.x;
  int w = tid >> 6, l = tid & 63, quad = l >> 4, l15 = l & 15;

  __shared__ __attribute__((aligned(16))) bf16 xs[32 * 264];

  {
    int row = tid >> 3;
    int seg = tid & 7;
    int grow = rb * 32 + row;          // grow = u*64 + n
    int u = grow >> 6, n = grow & 63;
    int line = lines[n * 64 + u];
    const bf16* src = embed + (size_t)line * H_ + seg * 32;
    bf16* dst = xs + row * 264 + seg * 32;
#pragma unroll
    for (int e = 0; e < 4; e++)
      *(bf16x8*)(dst + e * 8) = *(const bf16x8*)(src + e * 8);
  }
  __syncthreads();

  f32x4 acc[2][12];
#pragma unroll
  for (int mt = 0; mt < 2; mt++)
#pragma unroll
    for (int nt = 0; nt < 12; nt++) acc[mt][nt] = f32x4{0.f, 0.f, 0.f, 0.f};

#pragma unroll
  for (int ks = 0; ks < 8; ks++) {
    int koff = ks * 32 + quad * 8;
    bf16x8 a0 = *(const bf16x8*)(xs + l15 * 264 + koff);
    bf16x8 a1 = *(const bf16x8*)(xs + (l15 + 16) * 264 + koff);
#pragma unroll
    for (int nt = 0; nt < 12; nt++) {
      int g = (w * 12 + nt) * 16 + l15;
      bf16x8 b = *(const bf16x8*)(wi + (size_t)g * H_ + koff);
      acc[0][nt] = mfma_bf16(a0, b, acc[0][nt]);
      acc[1][nt] = mfma_bf16(a1, b, acc[1][nt]);
    }
  }

  size_t base = (size_t)dir * 4096 * 768;
#pragma unroll
  for (int nt = 0; nt < 12; nt++) {
    int g = (w * 12 + nt) * 16 + l15;
    float bias = (float)bi[g];
#pragma unroll
    for (int mt = 0; mt < 2; mt++)
#pragma unroll
      for (int r = 0; r < 4; r++) {
        int m = mt * 16 + quad * 4 + r;
        int grow = rb * 32 + m;
        xi[base + (size_t)grow * 768 + g] = (bf16)(acc[mt][nt][r] + bias);
      }
  }
}

// =====================================================================
// B2 v2: BiGRU over all rolls. 512 WGs x 512 thr, M=16 rows each.
// bx: xcd=bx&7 owns rolls [8*xcd, 8*xcd+8) (L2 locality: 8-u sliding
// window of xi stays resident per XCD). q=bx>>3: rsub=q&7, dir=(q>>3)&1,
// nq=q>>4. Wave w owns hidden cols [w*32,w*32+32) x 3 gates.
// Double-buffered hbuf -> 1 barrier/step.
// =====================================================================
__global__ __launch_bounds__(512, 2)
void k_bigru(const bf16* __restrict__ cw, const bf16* __restrict__ xi,
             const int* __restrict__ slot_map, unsigned char* __restrict__ K1c) {
  int bx = blockIdx.x;
  int xcd = bx & 7;
  int q = bx >> 3;
  int rsub = q & 7;
  int rest = q >> 3;
  int dir = rest & 1;
  int nq = rest >> 1;              // 0..3
  int roll = xcd * 8 + rsub;
  const bf16* wh = cw + (dir ? o_wh_b : o_wh_f);
  const bf16* bh = cw + (dir ? o_bh_b : o_bh_f);
  int tid = threadIdx.x;
  int w = tid >> 6, l = tid & 63, quad = l >> 4, l15 = l & 15;
  int cbase = w * 32;

  __shared__ __attribute__((aligned(16))) bf16 hb[2][16 * 264];
  for (int idx = tid; idx < 16 * 264; idx += 512) hb[0][idx] = (bf16)0.f;

  // copy-phase constants
  int crow = tid >> 5;             // 16 rows
  int cseg = tid & 31;             // 32 segs of 8 elems
  int n_copy = nq * 16 + crow;
  int kslot = slot_map[n_copy * 64 + roll];
  unsigned char* dstb =
      K1c + ((size_t)n_copy * 32 + (kslot < 0 ? 0 : kslot)) * 32768 + cseg * 8;

  float hreg[2][4];
#pragma unroll
  for (int c2 = 0; c2 < 2; c2++)
#pragma unroll
    for (int r = 0; r < 4; r++) hreg[c2][r] = 0.f;

  float bhv[3][2];
  const bf16* bp[3][2];
  int xco[3][2];
#pragma unroll
  for (int g = 0; g < 3; g++)
#pragma unroll
    for (int c2 = 0; c2 < 2; c2++) {
      int grow = g * 256 + cbase + c2 * 16 + l15;
      bhv[g][c2] = (float)bh[grow];
      bp[g][c2] = wh + (size_t)grow * 256 + quad * 8;
      xco[g][c2] = grow;  // same formula: g*256 + c
    }

  const bf16* xid = xi + (size_t)dir * 4096 * 768;
  __syncthreads();

  int cur = 0;
  for (int t = 0; t < 64; t++) {
    int u = (dir == 0) ? ((t - roll) & 63) : ((63 - t - roll) & 63);
    int j = (dir == 0) ? t : 63 - t;
    const bf16* xr = xid + ((size_t)u * 64 + nq * 16) * 768;

    // prefetch xi gate inputs (hits XCD-local L2 due to roll clustering)
    float xiv[3][2][4];
#pragma unroll
    for (int g = 0; g < 3; g++)
#pragma unroll
      for (int c2 = 0; c2 < 2; c2++)
#pragma unroll
        for (int r = 0; r < 4; r++)
          xiv[g][c2][r] = (float)xr[(quad * 4 + r) * 768 + xco[g][c2]];

    // gh = h_{t-1} @ wh^T  (M=16)
    f32x4 acc[3][2];
#pragma unroll
    for (int g = 0; g < 3; g++)
#pragma unroll
      for (int c2 = 0; c2 < 2; c2++) acc[g][c2] = f32x4{0.f, 0.f, 0.f, 0.f};

#pragma unroll
    for (int ks = 0; ks < 8; ks++) {
      int koff = ks * 32 + quad * 8;
      bf16x8 a0 = *(const bf16x8*)(hb[cur] + l15 * 264 + koff);
#pragma unroll
      for (int g = 0; g < 3; g++)
#pragma unroll
        for (int c2 = 0; c2 < 2; c2++) {
          bf16x8 b = *(const bf16x8*)(bp[g][c2] + ks * 32);
          acc[g][c2] = mfma_bf16(a0, b, acc[g][c2]);
        }
    }

    // gates: lane owns cells (row = quad*4+r, col = cbase + c2*16 + l15)
    int nxt = cur ^ 1;
#pragma unroll
    for (int c2 = 0; c2 < 2; c2++) {
#pragma unroll
      for (int r = 0; r < 4; r++) {
        float hr = acc[0][c2][r] + bhv[0][c2];
        float hz = acc[1][c2][r] + bhv[1][c2];
        float hn = acc[2][c2][r] + bhv[2][c2];
        float rg = sigmoid_f(xiv[0][c2][r] + hr);
        float zg = sigmoid_f(xiv[1][c2][r] + hz);
        float ng = tanh_f(xiv[2][c2][r] + rg * hn);
        hreg[c2][r] = (1.f - zg) * ng + zg * hreg[c2][r];
        hb[nxt][(quad * 4 + r) * 264 + cbase + c2 * 16 + l15] = (bf16)hreg[c2][r];
      }
    }
    __syncthreads();  // hb[nxt] complete; everyone past hb[cur] reads

    // fp8-encode + store new h row -> K1c (if this (n,roll) is ever used)
    if (kslot >= 0) {
      bf16x8 v = *(const bf16x8*)(hb[nxt] + crow * 264 + cseg * 8);
      uint32_t w0 = pack4_fp8((float)v[0], (float)v[1], (float)v[2], (float)v[3]);
      uint32_t w1 = pack4_fp8((float)v[4], (float)v[5], (float)v[6], (float)v[7]);
      *(uint2*)(dstb + (size_t)(j * 2 + dir) * 256) = make_uint2(w0, w1);
    }
    cur = nxt;
  }
}

// =====================================================================
// D1: gi = cell_wi @ relu(f_w2 @ relu(f_w1 @ obs + b1) + b2) + cell_bi
// =====================================================================
__global__ __launch_bounds__(256, 2)
void k_dec_gi(const void* __restrict__ cond_raw, const int* __restrict__ flags,
              const int* __restrict__ a_idx, const bf16* __restrict__ cw,
              float* __restrict__ gi) {
  int rb = blockIdx.x;
  int tid = threadIdx.x;
  int w = tid >> 6, l = tid & 63, quad = l >> 4, l15 = l & 15;
  const bf16* aemb = cw + o_aemb;
  const bf16* f_w1 = cw + o_f_w1;
  const bf16* f_b1 = cw + o_f_b1;
  const bf16* f_w2 = cw + o_f_w2;
  const bf16* f_b2 = cw + o_f_b2;
  const bf16* cell_wi = cw + o_cell_wi;
  const bf16* cell_bi = cw + o_cell_bi;
  bool cf32 = flags[0] != 0;

  __shared__ __attribute__((aligned(16))) bf16 obs[32 * 328];
  __shared__ __attribute__((aligned(16))) bf16 xf1[32 * 264];

  for (int e = tid; e < 32 * 320; e += 256) {
    int row = e / 320, col = e - row * 320;
    int grow = rb * 32 + row;
    int t = grow >> 6, n = grow & 63;
    float v;
    if (col < 64) {
      v = cf32 ? ((const float*)cond_raw)[(size_t)grow * 64 + col]
               : (float)((const bf16*)cond_raw)[(size_t)grow * 64 + col];
    } else {
      int ap = (t == 0) ? 0 : a_idx[(t - 1) * 64 + n];
      v = (float)aemb[ap * 256 + (col - 64)];
    }
    obs[row * 328 + col] = (bf16)v;
  }
  __syncthreads();

  { // GEMM1: K=320 -> relu -> xf1
    f32x4 acc[2][4];
#pragma unroll
    for (int mt = 0; mt < 2; mt++)
#pragma unroll
      for (int nt = 0; nt < 4; nt++) acc[mt][nt] = f32x4{0.f, 0.f, 0.f, 0.f};
#pragma unroll
    for (int ks = 0; ks < 10; ks++) {
      int koff = ks * 32 + quad * 8;
      bf16x8 a0 = *(const bf16x8*)(obs + l15 * 328 + koff);
      bf16x8 a1 = *(const bf16x8*)(obs + (l15 + 16) * 328 + koff);
#pragma unroll
      for (int nt = 0; nt < 4; nt++) {
        int g = (w * 4 + nt) * 16 + l15;
        bf16x8 b = *(const bf16x8*)(f_w1 + (size_t)g * 320 + koff);
        acc[0][nt] = mfma_bf16(a0, b, acc[0][nt]);
        acc[1][nt] = mfma_bf16(a1, b, acc[1][nt]);
      }
    }
#pragma unroll
    for (int nt = 0; nt < 4; nt++) {
      int g = (w * 4 + nt) * 16 + l15;
      float bias = (float)f_b1[g];
#pragma unroll
      for (int mt = 0; mt < 2; mt++)
#pragma unroll
        for (int r = 0; r < 4; r++) {
          int m = mt * 16 + quad * 4 + r;
          xf1[m * 264 + g] = (bf16)fmaxf(acc[mt][nt][r] + bias, 0.f);
        }
    }
  }
  __syncthreads();

  bf16* xf2 = obs;  // reuse (stride 264)
  { // GEMM2: K=256 -> relu -> xf2
    f32x4 acc[2][4];
#pragma unroll
    for (int mt = 0; mt < 2; mt++)
#pragma unroll
      for (int nt = 0; nt < 4; nt++) acc[mt][nt] = f32x4{0.f, 0.f, 0.f, 0.f};
#pragma unroll
    for (int ks = 0; ks < 8; ks++) {
      int koff = ks * 32 + quad * 8;
      bf16x8 a0 = *(const bf16x8*)(xf1 + l15 * 264 + koff);
      bf16x8 a1 = *(const bf16x8*)(xf1 + (l15 + 16) * 264 + koff);
#pragma unroll
      for (int nt = 0; nt < 4; nt++) {
        int g = (w * 4 + nt) * 16 + l15;
        bf16x8 b = *(const bf16x8*)(f_w2 + (size_t)g * 256 + koff);
        acc[0][nt] = mfma_bf16(a0, b, acc[0][nt]);
        acc[1][nt] = mfma_bf16(a1, b, acc[1][nt]);
      }
    }
#pragma unroll
    for (int nt = 0; nt < 4; nt++) {
      int g = (w * 4 + nt) * 16 + l15;
      float bias = (float)f_b2[g];
#pragma unroll
      for (int mt = 0; mt < 2; mt++)
#pragma unroll
        for (int r = 0; r < 4; r++) {
          int m = mt * 16 + quad * 4 + r;
          xf2[m * 264 + g] = (bf16)fmaxf(acc[mt][nt][r] + bias, 0.f);
        }
    }
  }
  __syncthreads();

  { // GEMM3: -> gi (f32, global)
    f32x4 acc[2][12];
#pragma unroll
    for (int mt = 0; mt < 2; mt++)
#pragma unroll
      for (int nt = 0; nt < 12; nt++) acc[mt][nt] = f32x4{0.f, 0.f, 0.f, 0.f};
#pragma unroll
    for (int ks = 0; ks < 8; ks++) {
      int koff = ks * 32 + quad * 8;
      bf16x8 a0 = *(const bf16x8*)(xf2 + l15 * 264 + koff);
      bf16x8 a1 = *(const bf16x8*)(xf2 + (l15 + 16) * 264 + koff);
#pragma unroll
      for (int nt = 0; nt < 12; nt++) {
        int g = (w * 12 + nt) * 16 + l15;
        bf16x8 b = *(const bf16x8*)(cell_wi + (size_t)g * 256 + koff);
        acc[0][nt] = mfma_bf16(a0, b, acc[0][nt]);
        acc[1][nt] = mfma_bf16(a1, b, acc[1][nt]);
      }
    }
#pragma unroll
    for (int nt = 0; nt < 12; nt++) {
      int g = (w * 12 + nt) * 16 + l15;
      float bias = (float)cell_bi[g];
#pragma unroll
      for (int mt = 0; mt < 2; mt++)
#pragma unroll
        for (int r = 0; r < 4; r++) {
          int m = mt * 16 + quad * 4 + r;
          int grow = rb * 32 + m;
          gi[(size_t)grow * 768 + g] = acc[mt][nt][r] + bias;
        }
    }
  }
}

// =====================================================================
// D2 v2: decoder GRU-cell recurrence, MFMA over M=16 batch rows.
// grid 4 WGs (nq) x 512 thr; T=32 steps; gi is f32; writes hdec f32.
// =====================================================================
__global__ __launch_bounds__(512, 2)
void k_dec_h(const bf16* __restrict__ cw, const float* __restrict__ gi,
             float* __restrict__ hdec) {
  int nq = blockIdx.x;             // 0..3
  const bf16* wh = cw + o_cell_wh;
  const bf16* bh = cw + o_cell_bh;
  int tid = threadIdx.x;
  int w = tid >> 6, l = tid & 63, quad = l >> 4, l15 = l & 15;
  int cbase = w * 32;

  __shared__ __attribute__((aligned(16))) bf16 hb[2][16 * 264];
  for (int idx = tid; idx < 16 * 264; idx += 512) hb[0][idx] = (bf16)0.f;

  float hreg[2][4];
#pragma unroll
  for (int c2 = 0; c2 < 2; c2++)
#pragma unroll
    for (int r = 0; r < 4; r++) hreg[c2][r] = 0.f;

  float bhv[3][2];
  const bf16* bp[3][2];
  int xco[3][2];
#pragma unroll
  for (int g = 0; g < 3; g++)
#pragma unroll
    for (int c2 = 0; c2 < 2; c2++) {
      int grow = g * 256 + cbase + c2 * 16 + l15;
      bhv[g][c2] = (float)bh[grow];
      bp[g][c2] = wh + (size_t)grow * 256 + quad * 8;
      xco[g][c2] = grow;
    }
  __syncthreads();

  int cur = 0;
  for (int t = 0; t < 32; t++) {
    const float* gr = gi + ((size_t)t * 64 + nq * 16) * 768;

    float giv[3][2][4];
#pragma unroll
    for (int g = 0; g < 3; g++)
#pragma unroll
      for (int c2 = 0; c2 < 2; c2++)
#pragma unroll
        for (int r = 0; r < 4; r++)
          giv[g][c2][r] = gr[(quad * 4 + r) * 768 + xco[g][c2]];

    f32x4 acc[3][2];
#pragma unroll
    for (int g = 0; g < 3; g++)
#pragma unroll
      for (int c2 = 0; c2 < 2; c2++) acc[g][c2] = f32x4{0.f, 0.f, 0.f, 0.f};

#pragma unroll
    for (int ks = 0; ks < 8; ks++) {
      int koff = ks * 32 + quad * 8;
      bf16x8 a0 = *(const bf16x8*)(hb[cur] + l15 * 264 + koff);
#pragma unroll
      for (int g = 0; g < 3; g++)
#pragma unroll
        for (int c2 = 0; c2 < 2; c2++) {
          bf16x8 b = *(const bf16x8*)(bp[g][c2] + ks * 32);
          acc[g][c2] = mfma_bf16(a0, b, acc[g][c2]);
        }
    }

    int nxt = cur ^ 1;
#pragma unroll
    for (int c2 = 0; c2 < 2; c2++) {
#pragma unroll
      for (int r = 0; r < 4; r++) {
        float hr = acc[0][c2][r] + bhv[0][c2];
        float hz = acc[1][c2][r] + bhv[1][c2];
        float hn = acc[2][c2][r] + bhv[2][c2];
        float rg = sigmoid_f(giv[0][c2][r] + hr);
        float zg = sigmoid_f(giv[1][c2][r] + hz);
        float ng = tanh_f(giv[2][c2][r] + rg * hn);
        float hnew = (1.f - zg) * ng + zg * hreg[c2][r];
        hreg[c2][r] = hnew;
        hb[nxt][(quad * 4 + r) * 264 + cbase + c2 * 16 + l15] = (bf16)hnew;
        // f32 h to hdec directly from registers
        hdec[((size_t)t * 64 + nq * 16 + quad * 4 + r) * 256 + cbase + c2 * 16 + l15] = hnew;
      }
    }
    __syncthreads();
    cur = nxt;
  }
}

// =====================================================================
// D3: heads + attention + output packing. grid 2048 WGs, 256 thr.
// =====================================================================
__global__ void k_dec_out(const float* __restrict__ hdec, const unsigned char* __restrict__ K1c,
                          const int* __restrict__ slot_map, const int* __restrict__ flags,
                          const int* __restrict__ a_idx, const int* __restrict__ p_idx,
                          const bf16* __restrict__ cw, void* __restrict__ out_raw) {
  int bx = blockIdx.x;
  int t = bx >> 6, n = bx & 63;
  int tid = threadIdx.x;
  int w = tid >> 6, l = tid & 63;
  const bf16* critic_w = cw + o_critic_w;
  const bf16* critic_b = cw + o_critic_b;
  const bf16* pointer_w = cw + o_pointer_w;
  const bf16* pointer_b = cw + o_pointer_b;
  const bf16* actor_w = cw + o_actor_w;
  const bf16* actor_b = cw + o_actor_b;
  const bf16* query_w = cw + o_query_w;
  const bf16* query_b = cw + o_query_b;

  __shared__ float hs[256], qs[256], ls[256], sA[256];
  __shared__ float pl[64], al[16], red[8], scal[4];
  __shared__ __attribute__((aligned(16))) unsigned char ksb[128 * 264];

  hs[tid] = hdec[((size_t)t * 64 + n) * 256 + tid];
  int p = p_idx[t * 64 + n];
  int slot = slot_map[n * 64 + p];
  {
    const uint32_t* kg = (const uint32_t*)(K1c + ((size_t)n * 32 + slot) * 32768);
#pragma unroll
    for (int e = 0; e < 8; e++) {
      int flat = (e * 256 + tid) * 16;
      int kk = flat >> 8, col = flat & 255;
      uint32_t w0 = kg[(flat >> 2) + 0], w1 = kg[(flat >> 2) + 1];
      uint32_t w2 = kg[(flat >> 2) + 2], w3 = kg[(flat >> 2) + 3];
      uint32_t* d0 = (uint32_t*)(ksb + kk * 264 + col);
      d0[0] = w0; d0[1] = w1; d0[2] = w2; d0[3] = w3;
    }
  }
  __syncthreads();

  { // q = h @ query_w^T + query_b
    float acc = (float)query_b[tid];
    const bf16* qw = query_w + (size_t)tid * 256;
#pragma unroll 4
    for (int k0 = 0; k0 < 256; k0 += 8) {
      bf16x8 wv = *(const bf16x8*)(qw + k0);
#pragma unroll
      for (int e = 0; e < 8; e++) acc += (float)wv[e] * hs[k0 + e];
    }
    qs[tid] = acc;
  }
  { // v partials
    float vp = hs[tid] * (float)critic_w[tid];
#pragma unroll
    for (int s = 32; s > 0; s >>= 1) vp += __shfl_down(vp, s, 64);
    if (l == 0) red[w] = vp;
  }
  { // pointer-logit partials
    int pp = tid >> 2, e = tid & 3;
    const bf16* pw = pointer_w + (size_t)pp * 256 + e * 64;
    float acc = 0.f;
#pragma unroll 8
    for (int hh = 0; hh < 64; hh++) acc += (float)pw[hh] * hs[e * 64 + hh];
    ls[tid] = acc;
  }
  __syncthreads();

  if (tid < 64) {
    float lg = ls[tid * 4] + ls[tid * 4 + 1] + ls[tid * 4 + 2] + ls[tid * 4 + 3] +
               (float)pointer_b[tid];
    float mx = lg;
#pragma unroll
    for (int m = 32; m > 0; m >>= 1) mx = fmaxf(mx, __shfl_xor(mx, m, 64));
    float ex = __expf(lg - mx);
    float sm = ex;
#pragma unroll
    for (int m = 32; m > 0; m >>= 1) sm += __shfl_xor(sm, m, 64);
    pl[tid] = ex / sm;
  }
  if (tid == 0) scal[0] = red[0] + red[1] + red[2] + red[3] + (float)critic_b[0];
  __syncthreads();

  { // l partials
    int kk = tid & 127, hc = tid >> 7;
    const uint32_t* kr = (const uint32_t*)(ksb + kk * 264 + hc * 128);
    const float* qr = qs + hc * 128;
    float acc = 0.f;
#pragma unroll 8
    for (int u = 0; u < 32; u++) {
      uint32_t b4 = kr[u];
      acc += __builtin_amdgcn_cvt_f32_fp8(b4, 0) * qr[u * 4 + 0];
      acc += __builtin_amdgcn_cvt_f32_fp8(b4, 1) * qr[u * 4 + 1];
      acc += __builtin_amdgcn_cvt_f32_fp8(b4, 2) * qr[u * 4 + 2];
      acc += __builtin_amdgcn_cvt_f32_fp8(b4, 3) * qr[u * 4 + 3];
    }
    ls[tid] = acc;
  }
  __syncthreads();
  if (tid < 128) ls[tid] += ls[tid + 128];
  __syncthreads();

  float zzv;
  {
    const unsigned char* kc = ksb + (tid & ~3);
    int sh = (tid & 3) * 8;
    float acc = 0.f;
#pragma unroll 8
    for (int kk = 0; kk < 128; kk++) {
      uint32_t d = *(const uint32_t*)(kc + kk * 264);
      acc += ls[kk] * __builtin_amdgcn_cvt_f32_fp8((int)(d >> sh), 0);
    }
    zzv = acc;
  }
  __syncthreads();
  qs[tid] = zzv;
  __syncthreads();

  {
    int a = tid >> 4, e = tid & 15;
    const bf16* aw = actor_w + (size_t)a * 256 + e * 16;
    const float* zr = qs + e * 16;
    float acc = 0.f;
#pragma unroll
    for (int hh = 0; hh < 16; hh++) acc += (float)aw[hh] * zr[hh];
    sA[tid] = acc;
  }
  __syncthreads();
  if (tid < 16) {
    float lg = (float)actor_b[tid];
#pragma unroll
    for (int e = 0; e < 16; e++) lg += sA[tid * 16 + e];
    float mx = lg;
#pragma unroll
    for (int m = 8; m > 0; m >>= 1) mx = fmaxf(mx, __shfl_xor(mx, m, 16));
    float ex = __expf(lg - mx);
    float sm = ex;
#pragma unroll
    for (int m = 8; m > 0; m >>= 1) sm += __shfl_xor(sm, m, 16);
    al[tid] = ex / sm;
  }
  __syncthreads();

  size_t rowoff = (size_t)(t * 64 + n) * 339;
  if (flags[1]) {
    float* ob = (float*)out_raw + rowoff;
    if (tid == 0) {
      ob[0] = (float)a_idx[t * 64 + n];
      ob[1] = (float)p;
      ob[2] = scal[0];
    }
    ob[3 + tid] = hs[tid];
    if (tid < 16) ob[259 + tid] = al[tid];
    if (tid < 64) ob[275 + tid] = pl[tid];
  } else {
    bf16* ob = (bf16*)out_raw + rowoff;
    if (tid == 0) {
      ob[0] = (bf16)(float)a_idx[t * 64 + n];
      ob[1] = (bf16)(float)p;
      ob[2] = (bf16)scal[0];
    }
    ob[3 + tid] = (bf16)hs[tid];
    if (tid < 16) ob[259 + tid] = (bf16)al[tid];
    if (tid < 64) ob[275 + tid] = (bf16)pl[tid];
  }
}

// =====================================================================
extern "C" void kernel_launch(void* const* d_in, const int* in_sizes, int n_in,
                              void* d_out, int out_size, void* d_ws, size_t ws_size,
                              hipStream_t stream) {
  (void)in_sizes; (void)n_in; (void)out_size; (void)ws_size;
  const void* condition = d_in[0];
  const int* lines      = (const int*)d_in[1];
  const int* a_idx      = (const int*)d_in[2];
  const int* p_idx      = (const int*)d_in[3];

  char* ws = (char*)d_ws;
  bf16* xi            = (bf16*)(ws + XI_OFF);
  unsigned char* K1c  = (unsigned char*)(ws + K1_OFF);
  float* gi           = (float*)(ws + GI_OFF);
  float* hdec         = (float*)(ws + HD_OFF);
  int* slot_map       = (int*)(ws + SLOT_OFF);
  int* flags          = (int*)(ws + FLG_OFF);
  bf16* cw            = (bf16*)(ws + CW_OFF);

  static const int src_idx[26] = {4, 5, 6, 7, 8, 9, 10, 11, 12, 13, 14, 15, 16,
                                  17, 18, 19, 20, 21, 22, 23, 24, 25, 26, 27, 28, 29};
  static const int offs[26] = {o_embed, o_aemb, o_wi_f, o_wh_f, o_bi_f, o_bh_f,
                               o_wi_b, o_wh_b, o_bi_b, o_bh_b, o_f_w1, o_f_b1,
                               o_f_w2, o_f_b2, o_cell_wi, o_cell_wh, o_cell_bi,
                               o_cell_bh, o_critic_w, o_critic_b, o_pointer_w,
                               o_pointer_b, o_actor_w, o_actor_b, o_query_w, o_query_b};
  static const int cnts[26] = {32768, 4096, 196608, 196608, 768, 768,
                               196608, 196608, 768, 768, 81920, 256,
                               65536, 256, 196608, 196608, 768,
                               768, 256, 1, 16384, 64, 4096, 16, 65536, 256};
  RepackArgs ra;
  int total = 0;
  for (int i = 0; i < 26; i++) {
    ra.src[i] = d_in[src_idx[i]];
    ra.off[i] = offs[i];
    ra.cnt[i] = cnts[i];
    total += cnts[i];
  }
  int nchunks = (total + 2047) / 2048;

  k_detect<<<1, 256, 0, stream>>>((const uint32_t*)condition, (const uint32_t*)d_in[4], flags);
  k_repack<<<nchunks, 256, 0, stream>>>(ra, flags, cw);
  k_slot<<<1, 64, 0, stream>>>(p_idx, slot_map);
  k_xi<<<256, 256, 0, stream>>>(lines, cw, xi);
  k_bigru<<<512, 512, 0, stream>>>(cw, xi, slot_map, K1c);
  k_dec_gi<<<64, 256, 0, stream>>>(condition, flags, a_idx, cw, gi);
  k_dec_h<<<4, 512, 0, stream>>>(cw, gi, hdec);
  k_dec_out<<<2048, 256, 0, stream>>>(hdec, K1c, slot_map, flags, a_idx, p_idx, cw, d_out);
}

// Round 5
// 752.659 us; speedup vs baseline: 1.9441x; 1.5761x over previous
//
#include <hip/hip_runtime.h>
#include <hip/hip_bf16.h>
#include <cstddef>
#include <cstdint>

// ---------- types ----------
typedef __bf16 bf16;
typedef bf16 bf16x8 __attribute__((ext_vector_type(8)));
typedef float f32x4 __attribute__((ext_vector_type(4)));

#define DEV static __device__ __forceinline__

DEV f32x4 mfma_bf16(bf16x8 a, bf16x8 b, f32x4 c) {
  return __builtin_amdgcn_mfma_f32_16x16x32_bf16(a, b, c, 0, 0, 0);
}
DEV f32x4 mfma_fp8(long a, long b, f32x4 c) {
  return __builtin_amdgcn_mfma_f32_16x16x32_fp8_fp8(a, b, c, 0, 0, 0);
}

DEV float sigmoid_f(float x) { return 1.0f / (1.0f + __expf(-x)); }
DEV float tanh_f(float x) {
  float ax = fabsf(x);
  float e = __expf(-2.0f * ax);
  float t = 1.0f - 2.0f * e / (1.0f + e);
  return copysignf(t, x);
}

DEV unsigned char fp8_of(float x) {
  return (unsigned char)(__builtin_amdgcn_cvt_pk_fp8_f32(x, x, 0, false) & 0xFF);
}

// ---------- problem constants ----------
// T=32, N=64, C=64, L=64, H=256, NA=16, NL=128
static constexpr int H_ = 256;

// ---------- canonical bf16 weight region: element offsets ----------
static constexpr int o_embed = 0;            // 32768
static constexpr int o_aemb = 32768;         // 4096
static constexpr int o_wi_f = 36864;         // 196608
static constexpr int o_wh_f = 233472;        // 196608
static constexpr int o_bi_f = 430080;        // 768
static constexpr int o_bh_f = 430848;        // 768
static constexpr int o_wi_b = 431616;        // 196608
static constexpr int o_wh_b = 628224;        // 196608
static constexpr int o_bi_b = 824832;        // 768
static constexpr int o_bh_b = 825600;        // 768
static constexpr int o_f_w1 = 826368;        // 81920
static constexpr int o_f_b1 = 908288;        // 256
static constexpr int o_f_w2 = 908544;        // 65536
static constexpr int o_f_b2 = 974080;        // 256
static constexpr int o_cell_wi = 974336;     // 196608
static constexpr int o_cell_wh = 1170944;    // 196608
static constexpr int o_cell_bi = 1367552;    // 768
static constexpr int o_cell_bh = 1368320;    // 768
static constexpr int o_critic_w = 1369088;   // 256
static constexpr int o_critic_b = 1369344;   // 1 (padded 16)
static constexpr int o_pointer_w = 1369360;  // 16384
static constexpr int o_pointer_b = 1385744;  // 64
static constexpr int o_actor_w = 1385808;    // 4096
static constexpr int o_actor_b = 1389904;    // 16
static constexpr int o_query_w = 1389920;    // 65536
static constexpr int o_query_b = 1455456;    // 256
static constexpr int CW_TOTAL = 1455712;     // elements

// ---------- workspace layout (bytes), total ~92 MB ----------
static constexpr size_t XI_OFF = 0;                               // bf16 [2][64 u][64 n][768]
static constexpr size_t XI_BYTES = 2ull * 64 * 64 * 768 * 2;      // 12,582,912
static constexpr size_t K1_OFF = XI_OFF + XI_BYTES;               // fp8 [64 n][32 slot][128 row][256]
static constexpr size_t K1_BYTES = 64ull * 32 * 128 * 256;        // 67,108,864
static constexpr size_t GI_OFF = K1_OFF + K1_BYTES;               // f32 [32][64][768]
static constexpr size_t GI_BYTES = 32ull * 64 * 768 * 4;          // 6,291,456
static constexpr size_t HD_OFF = GI_OFF + GI_BYTES;               // f32 [32][64][256]
static constexpr size_t HD_BYTES = 32ull * 64 * 256 * 4;          // 2,097,152
static constexpr size_t SLOT_OFF = HD_OFF + HD_BYTES;             // i32 [64 n][64 roll]
static constexpr size_t SLOT_BYTES = 64ull * 64 * 4;
static constexpr size_t FLG_OFF = SLOT_OFF + SLOT_BYTES;          // i32 [2]
static constexpr size_t FLG_BYTES = 256;
static constexpr size_t CW_OFF = FLG_OFF + FLG_BYTES;             // bf16 canonical weights
static constexpr size_t CW_BYTES = (size_t)CW_TOTAL * 2;          // 2,911,424
static constexpr size_t WH8_OFF = ((CW_OFF + CW_BYTES + 255) / 256) * 256;  // fp8 [2][768][256]
static constexpr size_t WH8_BYTES = 2ull * 768 * 256;

// =====================================================================
// D0: dtype detection (bf16 vs f32 storage). 1024 samples each.
// =====================================================================
__global__ void k_detect(const uint32_t* __restrict__ cond, const uint32_t* __restrict__ emb,
                         int* __restrict__ flags) {
  __shared__ int votes0[256], votes1[256];
  int tid = threadIdx.x;
  int c0 = 0, c1 = 0;
#pragma unroll
  for (int j = 0; j < 4; j++) {
    uint32_t wc = cond[tid * 4 + j];
    uint32_t we = emb[tid * 4 + j];
    int ec = (int)((wc >> 7) & 0xFF);
    int ee = (int)((we >> 7) & 0xFF);
    c0 += (ec >= 96 && ec <= 130) ? 1 : 0;
    c1 += (ee >= 96 && ee <= 130) ? 1 : 0;
  }
  votes0[tid] = c0;
  votes1[tid] = c1;
  __syncthreads();
  if (tid == 0) {
    int s0 = 0, s1 = 0;
    for (int i = 0; i < 256; i++) { s0 += votes0[i]; s1 += votes1[i]; }
    flags[0] = (s0 < 512) ? 1 : 0;
    flags[1] = (s1 < 512) ? 1 : 0;
  }
}

// =====================================================================
// D0b: repack all float weight arrays into canonical bf16 region.
// =====================================================================
struct RepackArgs {
  const void* src[26];
  int off[26];
  int cnt[26];
};

__global__ void k_repack(RepackArgs args, const int* __restrict__ flags,
                         bf16* __restrict__ cw) {
  bool f32w = flags[1] != 0;
  int gidx = blockIdx.x * 2048 + threadIdx.x;
  for (int e = 0; e < 8; e++, gidx += 256) {
    int rem = gidx, s = 0;
    while (s < 26 && rem >= args.cnt[s]) { rem -= args.cnt[s]; s++; }
    if (s >= 26) return;
    float v = f32w ? ((const float*)args.src[s])[rem]
                   : (float)((const bf16*)args.src[s])[rem];
    cw[args.off[s] + rem] = (bf16)v;
  }
}

// =====================================================================
// D0c: fp8 copy of wh_f / wh_b (reads canonical bf16). 384 x 1024.
// =====================================================================
__global__ void k_repack8(const bf16* __restrict__ cw, unsigned char* __restrict__ wh8) {
  int i = blockIdx.x * 1024 + threadIdx.x;  // < 393216
  float v = (i < 196608) ? (float)cw[o_wh_f + i] : (float)cw[o_wh_b + (i - 196608)];
  wh8[i] = fp8_of(v);
}

// =====================================================================
// S0: slot_map[n][roll] = compact slot id or -1.  1 WG x 256 thr, LDS-staged.
// =====================================================================
__global__ void k_slot(const int* __restrict__ p_idx, int* __restrict__ slot_map) {
  __shared__ int pbuf[2048];
  __shared__ signed char sm[64 * 64];
  int tid = threadIdx.x;  // 256
  for (int i = tid; i < 2048; i += 256) pbuf[i] = p_idx[i];
  for (int i = tid; i < 4096; i += 256) sm[i] = -1;
  __syncthreads();
  if (tid < 64) {
    int n = tid;
    int cnt = 0;
    for (int t = 0; t < 32; t++) {
      int p = pbuf[t * 64 + n];
      if (sm[n * 64 + p] < 0) sm[n * 64 + p] = (signed char)(cnt++);
    }
  }
  __syncthreads();
  for (int i = tid; i < 4096; i += 256) slot_map[i] = (int)sm[i];
}

// =====================================================================
// B1: xi[d][u][n][g] = embed[lines[n][u]] @ wi_d^T + bi_d   (bf16 out)
// =====================================================================
__global__ __launch_bounds__(256, 2)
void k_xi(const int* __restrict__ lines, const bf16* __restrict__ cw,
          bf16* __restrict__ xi) {
  int bx = blockIdx.x;
  int dir = bx & 1, rb = bx >> 1;
  const bf16* embed = cw + o_embed;
  const bf16* wi = cw + (dir ? o_wi_b : o_wi_f);
  const bf16* bi = cw + (dir ? o_bi_b : o_bi_f);
  int tid = threadIdx.x;
  int w = tid >> 6, l = tid & 63, quad = l >> 4, l15 = l & 15;

  __shared__ __attribute__((aligned(16))) bf16 xs[32 * 264];

  {
    int row = tid >> 3;
    int seg = tid & 7;
    int grow = rb * 32 + row;          // grow = u*64 + n
    int u = grow >> 6, n = grow & 63;
    int line = lines[n * 64 + u];
    const bf16* src = embed + (size_t)line * H_ + seg * 32;
    bf16* dst = xs + row * 264 + seg * 32;
#pragma unroll
    for (int e = 0; e < 4; e++)
      *(bf16x8*)(dst + e * 8) = *(const bf16x8*)(src + e * 8);
  }
  __syncthreads();

  f32x4 acc[2][12];
#pragma unroll
  for (int mt = 0; mt < 2; mt++)
#pragma unroll
    for (int nt = 0; nt < 12; nt++) acc[mt][nt] = f32x4{0.f, 0.f, 0.f, 0.f};

#pragma unroll
  for (int ks = 0; ks < 8; ks++) {
    int koff = ks * 32 + quad * 8;
    bf16x8 a0 = *(const bf16x8*)(xs + l15 * 264 + koff);
    bf16x8 a1 = *(const bf16x8*)(xs + (l15 + 16) * 264 + koff);
#pragma unroll
    for (int nt = 0; nt < 12; nt++) {
      int g = (w * 12 + nt) * 16 + l15;
      bf16x8 b = *(const bf16x8*)(wi + (size_t)g * H_ + koff);
      acc[0][nt] = mfma_bf16(a0, b, acc[0][nt]);
      acc[1][nt] = mfma_bf16(a1, b, acc[1][nt]);
    }
  }

  size_t base = (size_t)dir * 4096 * 768;
#pragma unroll
  for (int nt = 0; nt < 12; nt++) {
    int g = (w * 12 + nt) * 16 + l15;
    float bias = (float)bi[g];
#pragma unroll
    for (int mt = 0; mt < 2; mt++)
#pragma unroll
      for (int r = 0; r < 4; r++) {
        int m = mt * 16 + quad * 4 + r;
        int grow = rb * 32 + m;
        xi[base + (size_t)grow * 768 + g] = (bf16)(acc[mt][nt][r] + bias);
      }
  }
}

// =====================================================================
// B2 v3: BiGRU, fp8 wh + fp8 h, M=32 (2 adjacent rolls x 16 n).
// grid 256 WGs x 1024 thr (16 waves). xcd=bx&7 owns rolls [8xcd,8xcd+8).
// q=bx>>3: rp=q&3 (roll pair), dir=(q>>2)&1, nq=q>>3.
// Wave w owns hidden cols [16w,16w+16) x 3 gates (gate combine in-lane).
// Double-buffered fp8 hbuf, 1 barrier/step.
// =====================================================================
__global__ __launch_bounds__(1024)
void k_bigru(const bf16* __restrict__ cw, const unsigned char* __restrict__ wh8,
             const bf16* __restrict__ xi, const int* __restrict__ slot_map,
             unsigned char* __restrict__ K1c) {
  int bx = blockIdx.x;
  int xcd = bx & 7;
  int q = bx >> 3;            // 0..31
  int rp = q & 3;
  int dir = (q >> 2) & 1;
  int nq = q >> 3;            // 0..3
  int roll0 = xcd * 8 + rp * 2;
  const unsigned char* wh = wh8 + (size_t)dir * 196608;
  const bf16* bh = cw + (dir ? o_bh_b : o_bh_f);
  int tid = threadIdx.x;
  int w = tid >> 6;           // 0..15 col-tile
  int l = tid & 63, quad = l >> 4, l15 = l & 15;
  int c = w * 16 + l15;       // owned hidden col

  __shared__ __attribute__((aligned(16))) unsigned char hb[2][32 * 264];
  for (int idx = tid; idx < 32 * 264; idx += 1024) hb[0][idx] = 0;  // h=0

  // K1c copy-phase constants: thread -> (row crow of 32, 8-byte seg)
  int crow = tid >> 5, cseg = tid & 31;
  int n_c = nq * 16 + (crow & 15);
  int roll_c = roll0 + (crow >> 4);
  int kslot = slot_map[n_c * 64 + roll_c];
  unsigned char* dstb =
      K1c + ((size_t)n_c * 32 + (kslot < 0 ? 0 : kslot)) * 32768 + cseg * 8;

  float hreg[2][4];
#pragma unroll
  for (int mt = 0; mt < 2; mt++)
#pragma unroll
    for (int r = 0; r < 4; r++) hreg[mt][r] = 0.f;

  float bhv[3];
  const unsigned char* bp[3];
  int xoff[3][4];
#pragma unroll
  for (int g = 0; g < 3; g++) {
    int grow = g * 256 + c;
    bhv[g] = (float)bh[grow];
    bp[g] = wh + (size_t)grow * 256 + quad * 8;
#pragma unroll
    for (int r = 0; r < 4; r++) xoff[g][r] = (quad * 4 + r) * 768 + grow;
  }

  const bf16* xnq = xi + (size_t)dir * 4096 * 768 + (size_t)nq * 16 * 768;
  __syncthreads();

  int cur = 0;
  for (int t = 0; t < 64; t++) {
    int j = dir ? (63 - t) : t;
    const bf16* xr[2];
#pragma unroll
    for (int mt = 0; mt < 2; mt++) {
      int roll = roll0 + mt;
      int u = dir ? ((63 - t - roll) & 63) : ((t - roll) & 63);
      xr[mt] = xnq + (size_t)u * (64 * 768);
    }
    // prefetch xi gate inputs (XCD-local L2)
    float xiv[3][2][4];
#pragma unroll
    for (int g = 0; g < 3; g++)
#pragma unroll
      for (int mt = 0; mt < 2; mt++)
#pragma unroll
        for (int r = 0; r < 4; r++) xiv[g][mt][r] = (float)xr[mt][xoff[g][r]];

    // gh = h_{t-1} @ wh^T (fp8 x fp8 -> f32)
    f32x4 acc[3][2];
#pragma unroll
    for (int g = 0; g < 3; g++)
#pragma unroll
      for (int mt = 0; mt < 2; mt++) acc[g][mt] = f32x4{0.f, 0.f, 0.f, 0.f};

#pragma unroll
    for (int ks = 0; ks < 8; ks++) {
      int ko = ks * 32 + quad * 8;
      long a0 = *(const long*)(hb[cur] + l15 * 264 + ko);
      long a1 = *(const long*)(hb[cur] + (16 + l15) * 264 + ko);
#pragma unroll
      for (int g = 0; g < 3; g++) {
        long b = *(const long*)(bp[g] + ks * 32);
        acc[g][0] = mfma_fp8(a0, b, acc[g][0]);
        acc[g][1] = mfma_fp8(a1, b, acc[g][1]);
      }
    }

    int nxt = cur ^ 1;
#pragma unroll
    for (int mt = 0; mt < 2; mt++) {
#pragma unroll
      for (int r = 0; r < 4; r++) {
        float hr = acc[0][mt][r] + bhv[0];
        float hz = acc[1][mt][r] + bhv[1];
        float hn = acc[2][mt][r] + bhv[2];
        float rg = sigmoid_f(xiv[0][mt][r] + hr);
        float zg = sigmoid_f(xiv[1][mt][r] + hz);
        float ng = tanh_f(xiv[2][mt][r] + rg * hn);
        hreg[mt][r] = (1.f - zg) * ng + zg * hreg[mt][r];
        int row = mt * 16 + quad * 4 + r;
        hb[nxt][row * 264 + c] = fp8_of(hreg[mt][r]);
      }
    }
    __syncthreads();  // hb[nxt] complete

    if (kslot >= 0) {
      *(uint2*)(dstb + (size_t)(j * 2 + dir) * 256) =
          *(const uint2*)(hb[nxt] + crow * 264 + cseg * 8);
    }
    cur = nxt;
  }
}

// =====================================================================
// D1: gi = cell_wi @ relu(f_w2 @ relu(f_w1 @ obs + b1) + b2) + cell_bi
// =====================================================================
__global__ __launch_bounds__(256, 2)
void k_dec_gi(const void* __restrict__ cond_raw, const int* __restrict__ flags,
              const int* __restrict__ a_idx, const bf16* __restrict__ cw,
              float* __restrict__ gi) {
  int rb = blockIdx.x;
  int tid = threadIdx.x;
  int w = tid >> 6, l = tid & 63, quad = l >> 4, l15 = l & 15;
  const bf16* aemb = cw + o_aemb;
  const bf16* f_w1 = cw + o_f_w1;
  const bf16* f_b1 = cw + o_f_b1;
  const bf16* f_w2 = cw + o_f_w2;
  const bf16* f_b2 = cw + o_f_b2;
  const bf16* cell_wi = cw + o_cell_wi;
  const bf16* cell_bi = cw + o_cell_bi;
  bool cf32 = flags[0] != 0;

  __shared__ __attribute__((aligned(16))) bf16 obs[32 * 328];
  __shared__ __attribute__((aligned(16))) bf16 xf1[32 * 264];

  for (int e = tid; e < 32 * 320; e += 256) {
    int row = e / 320, col = e - row * 320;
    int grow = rb * 32 + row;
    int t = grow >> 6, n = grow & 63;
    float v;
    if (col < 64) {
      v = cf32 ? ((const float*)cond_raw)[(size_t)grow * 64 + col]
               : (float)((const bf16*)cond_raw)[(size_t)grow * 64 + col];
    } else {
      int ap = (t == 0) ? 0 : a_idx[(t - 1) * 64 + n];
      v = (float)aemb[ap * 256 + (col - 64)];
    }
    obs[row * 328 + col] = (bf16)v;
  }
  __syncthreads();

  { // GEMM1: K=320 -> relu -> xf1
    f32x4 acc[2][4];
#pragma unroll
    for (int mt = 0; mt < 2; mt++)
#pragma unroll
      for (int nt = 0; nt < 4; nt++) acc[mt][nt] = f32x4{0.f, 0.f, 0.f, 0.f};
#pragma unroll
    for (int ks = 0; ks < 10; ks++) {
      int koff = ks * 32 + quad * 8;
      bf16x8 a0 = *(const bf16x8*)(obs + l15 * 328 + koff);
      bf16x8 a1 = *(const bf16x8*)(obs + (l15 + 16) * 328 + koff);
#pragma unroll
      for (int nt = 0; nt < 4; nt++) {
        int g = (w * 4 + nt) * 16 + l15;
        bf16x8 b = *(const bf16x8*)(f_w1 + (size_t)g * 320 + koff);
        acc[0][nt] = mfma_bf16(a0, b, acc[0][nt]);
        acc[1][nt] = mfma_bf16(a1, b, acc[1][nt]);
      }
    }
#pragma unroll
    for (int nt = 0; nt < 4; nt++) {
      int g = (w * 4 + nt) * 16 + l15;
      float bias = (float)f_b1[g];
#pragma unroll
      for (int mt = 0; mt < 2; mt++)
#pragma unroll
        for (int r = 0; r < 4; r++) {
          int m = mt * 16 + quad * 4 + r;
          xf1[m * 264 + g] = (bf16)fmaxf(acc[mt][nt][r] + bias, 0.f);
        }
    }
  }
  __syncthreads();

  bf16* xf2 = obs;  // reuse (stride 264)
  { // GEMM2: K=256 -> relu -> xf2
    f32x4 acc[2][4];
#pragma unroll
    for (int mt = 0; mt < 2; mt++)
#pragma unroll
      for (int nt = 0; nt < 4; nt++) acc[mt][nt] = f32x4{0.f, 0.f, 0.f, 0.f};
#pragma unroll
    for (int ks = 0; ks < 8; ks++) {
      int koff = ks * 32 + quad * 8;
      bf16x8 a0 = *(const bf16x8*)(xf1 + l15 * 264 + koff);
      bf16x8 a1 = *(const bf16x8*)(xf1 + (l15 + 16) * 264 + koff);
#pragma unroll
      for (int nt = 0; nt < 4; nt++) {
        int g = (w * 4 + nt) * 16 + l15;
        bf16x8 b = *(const bf16x8*)(f_w2 + (size_t)g * 256 + koff);
        acc[0][nt] = mfma_bf16(a0, b, acc[0][nt]);
        acc[1][nt] = mfma_bf16(a1, b, acc[1][nt]);
      }
    }
#pragma unroll
    for (int nt = 0; nt < 4; nt++) {
      int g = (w * 4 + nt) * 16 + l15;
      float bias = (float)f_b2[g];
#pragma unroll
      for (int mt = 0; mt < 2; mt++)
#pragma unroll
        for (int r = 0; r < 4; r++) {
          int m = mt * 16 + quad * 4 + r;
          xf2[m * 264 + g] = (bf16)fmaxf(acc[mt][nt][r] + bias, 0.f);
        }
    }
  }
  __syncthreads();

  { // GEMM3: -> gi (f32, global)
    f32x4 acc[2][12];
#pragma unroll
    for (int mt = 0; mt < 2; mt++)
#pragma unroll
      for (int nt = 0; nt < 12; nt++) acc[mt][nt] = f32x4{0.f, 0.f, 0.f, 0.f};
#pragma unroll
    for (int ks = 0; ks < 8; ks++) {
      int koff = ks * 32 + quad * 8;
      bf16x8 a0 = *(const bf16x8*)(xf2 + l15 * 264 + koff);
      bf16x8 a1 = *(const bf16x8*)(xf2 + (l15 + 16) * 264 + koff);
#pragma unroll
      for (int nt = 0; nt < 12; nt++) {
        int g = (w * 12 + nt) * 16 + l15;
        bf16x8 b = *(const bf16x8*)(cell_wi + (size_t)g * 256 + koff);
        acc[0][nt] = mfma_bf16(a0, b, acc[0][nt]);
        acc[1][nt] = mfma_bf16(a1, b, acc[1][nt]);
      }
    }
#pragma unroll
    for (int nt = 0; nt < 12; nt++) {
      int g = (w * 12 + nt) * 16 + l15;
      float bias = (float)cell_bi[g];
#pragma unroll
      for (int mt = 0; mt < 2; mt++)
#pragma unroll
        for (int r = 0; r < 4; r++) {
          int m = mt * 16 + quad * 4 + r;
          int grow = rb * 32 + m;
          gi[(size_t)grow * 768 + g] = acc[mt][nt][r] + bias;
        }
    }
  }
}

// =====================================================================
// D2: decoder GRU-cell recurrence, MFMA over M=16 batch rows.
// grid 4 WGs (nq) x 512 thr; T=32 steps.
// =====================================================================
__global__ __launch_bounds__(512, 2)
void k_dec_h(const bf16* __restrict__ cw, const float* __restrict__ gi,
             float* __restrict__ hdec) {
  int nq = blockIdx.x;             // 0..3
  const bf16* wh = cw + o_cell_wh;
  const bf16* bh = cw + o_cell_bh;
  int tid = threadIdx.x;
  int w = tid >> 6, l = tid & 63, quad = l >> 4, l15 = l & 15;
  int cbase = w * 32;

  __shared__ __attribute__((aligned(16))) bf16 hb[2][16 * 264];
  for (int idx = tid; idx < 16 * 264; idx += 512) hb[0][idx] = (bf16)0.f;

  float hreg[2][4];
#pragma unroll
  for (int c2 = 0; c2 < 2; c2++)
#pragma unroll
    for (int r = 0; r < 4; r++) hreg[c2][r] = 0.f;

  float bhv[3][2];
  const bf16* bp[3][2];
  int xco[3][2];
#pragma unroll
  for (int g = 0; g < 3; g++)
#pragma unroll
    for (int c2 = 0; c2 < 2; c2++) {
      int grow = g * 256 + cbase + c2 * 16 + l15;
      bhv[g][c2] = (float)bh[grow];
      bp[g][c2] = wh + (size_t)grow * 256 + quad * 8;
      xco[g][c2] = grow;
    }
  __syncthreads();

  int cur = 0;
  for (int t = 0; t < 32; t++) {
    const float* gr = gi + ((size_t)t * 64 + nq * 16) * 768;

    float giv[3][2][4];
#pragma unroll
    for (int g = 0; g < 3; g++)
#pragma unroll
      for (int c2 = 0; c2 < 2; c2++)
#pragma unroll
        for (int r = 0; r < 4; r++)
          giv[g][c2][r] = gr[(quad * 4 + r) * 768 + xco[g][c2]];

    f32x4 acc[3][2];
#pragma unroll
    for (int g = 0; g < 3; g++)
#pragma unroll
      for (int c2 = 0; c2 < 2; c2++) acc[g][c2] = f32x4{0.f, 0.f, 0.f, 0.f};

#pragma unroll
    for (int ks = 0; ks < 8; ks++) {
      int koff = ks * 32 + quad * 8;
      bf16x8 a0 = *(const bf16x8*)(hb[cur] + l15 * 264 + koff);
#pragma unroll
      for (int g = 0; g < 3; g++)
#pragma unroll
        for (int c2 = 0; c2 < 2; c2++) {
          bf16x8 b = *(const bf16x8*)(bp[g][c2] + ks * 32);
          acc[g][c2] = mfma_bf16(a0, b, acc[g][c2]);
        }
    }

    int nxt = cur ^ 1;
#pragma unroll
    for (int c2 = 0; c2 < 2; c2++) {
#pragma unroll
      for (int r = 0; r < 4; r++) {
        float hr = acc[0][c2][r] + bhv[0][c2];
        float hz = acc[1][c2][r] + bhv[1][c2];
        float hn = acc[2][c2][r] + bhv[2][c2];
        float rg = sigmoid_f(giv[0][c2][r] + hr);
        float zg = sigmoid_f(giv[1][c2][r] + hz);
        float ng = tanh_f(giv[2][c2][r] + rg * hn);
        float hnew = (1.f - zg) * ng + zg * hreg[c2][r];
        hreg[c2][r] = hnew;
        hb[nxt][(quad * 4 + r) * 264 + cbase + c2 * 16 + l15] = (bf16)hnew;
        hdec[((size_t)t * 64 + nq * 16 + quad * 4 + r) * 256 + cbase + c2 * 16 + l15] = hnew;
      }
    }
    __syncthreads();
    cur = nxt;
  }
}

// =====================================================================
// D3: heads + attention + output packing. grid 2048 WGs, 256 thr.
// =====================================================================
__global__ void k_dec_out(const float* __restrict__ hdec, const unsigned char* __restrict__ K1c,
                          const int* __restrict__ slot_map, const int* __restrict__ flags,
                          const int* __restrict__ a_idx, const int* __restrict__ p_idx,
                          const bf16* __restrict__ cw, void* __restrict__ out_raw) {
  int bx = blockIdx.x;
  int t = bx >> 6, n = bx & 63;
  int tid = threadIdx.x;
  int w = tid >> 6, l = tid & 63;
  const bf16* critic_w = cw + o_critic_w;
  const bf16* critic_b = cw + o_critic_b;
  const bf16* pointer_w = cw + o_pointer_w;
  const bf16* pointer_b = cw + o_pointer_b;
  const bf16* actor_w = cw + o_actor_w;
  const bf16* actor_b = cw + o_actor_b;
  const bf16* query_w = cw + o_query_w;
  const bf16* query_b = cw + o_query_b;

  __shared__ float hs[256], qs[256], ls[256], sA[256];
  __shared__ float pl[64], al[16], red[8], scal[4];
  __shared__ __attribute__((aligned(16))) unsigned char ksb[128 * 264];

  hs[tid] = hdec[((size_t)t * 64 + n) * 256 + tid];
  int p = p_idx[t * 64 + n];
  int slot = slot_map[n * 64 + p];
  {
    const uint32_t* kg = (const uint32_t*)(K1c + ((size_t)n * 32 + slot) * 32768);
#pragma unroll
    for (int e = 0; e < 8; e++) {
      int flat = (e * 256 + tid) * 16;
      int kk = flat >> 8, col = flat & 255;
      uint32_t w0 = kg[(flat >> 2) + 0], w1 = kg[(flat >> 2) + 1];
      uint32_t w2 = kg[(flat >> 2) + 2], w3 = kg[(flat >> 2) + 3];
      uint32_t* d0 = (uint32_t*)(ksb + kk * 264 + col);
      d0[0] = w0; d0[1] = w1; d0[2] = w2; d0[3] = w3;
    }
  }
  __syncthreads();

  { // q = h @ query_w^T + query_b
    float acc = (float)query_b[tid];
    const bf16* qw = query_w + (size_t)tid * 256;
#pragma unroll 4
    for (int k0 = 0; k0 < 256; k0 += 8) {
      bf16x8 wv = *(const bf16x8*)(qw + k0);
#pragma unroll
      for (int e = 0; e < 8; e++) acc += (float)wv[e] * hs[k0 + e];
    }
    qs[tid] = acc;
  }
  { // v partials
    float vp = hs[tid] * (float)critic_w[tid];
#pragma unroll
    for (int s = 32; s > 0; s >>= 1) vp += __shfl_down(vp, s, 64);
    if (l == 0) red[w] = vp;
  }
  { // pointer-logit partials
    int pp = tid >> 2, e = tid & 3;
    const bf16* pw = pointer_w + (size_t)pp * 256 + e * 64;
    float acc = 0.f;
#pragma unroll 8
    for (int hh = 0; hh < 64; hh++) acc += (float)pw[hh] * hs[e * 64 + hh];
    ls[tid] = acc;
  }
  __syncthreads();

  if (tid < 64) {
    float lg = ls[tid * 4] + ls[tid * 4 + 1] + ls[tid * 4 + 2] + ls[tid * 4 + 3] +
               (float)pointer_b[tid];
    float mx = lg;
#pragma unroll
    for (int m = 32; m > 0; m >>= 1) mx = fmaxf(mx, __shfl_xor(mx, m, 64));
    float ex = __expf(lg - mx);
    float sm = ex;
#pragma unroll
    for (int m = 32; m > 0; m >>= 1) sm += __shfl_xor(sm, m, 64);
    pl[tid] = ex / sm;
  }
  if (tid == 0) scal[0] = red[0] + red[1] + red[2] + red[3] + (float)critic_b[0];
  __syncthreads();

  { // l partials
    int kk = tid & 127, hc = tid >> 7;
    const uint32_t* kr = (const uint32_t*)(ksb + kk * 264 + hc * 128);
    const float* qr = qs + hc * 128;
    float acc = 0.f;
#pragma unroll 8
    for (int u = 0; u < 32; u++) {
      uint32_t b4 = kr[u];
      acc += __builtin_amdgcn_cvt_f32_fp8(b4, 0) * qr[u * 4 + 0];
      acc += __builtin_amdgcn_cvt_f32_fp8(b4, 1) * qr[u * 4 + 1];
      acc += __builtin_amdgcn_cvt_f32_fp8(b4, 2) * qr[u * 4 + 2];
      acc += __builtin_amdgcn_cvt_f32_fp8(b4, 3) * qr[u * 4 + 3];
    }
    ls[tid] = acc;
  }
  __syncthreads();
  if (tid < 128) ls[tid] += ls[tid + 128];
  __syncthreads();

  float zzv;
  {
    const unsigned char* kc = ksb + (tid & ~3);
    int sh = (tid & 3) * 8;
    float acc = 0.f;
#pragma unroll 8
    for (int kk = 0; kk < 128; kk++) {
      uint32_t d = *(const uint32_t*)(kc + kk * 264);
      acc += ls[kk] * __builtin_amdgcn_cvt_f32_fp8((int)(d >> sh), 0);
    }
    zzv = acc;
  }
  __syncthreads();
  qs[tid] = zzv;
  __syncthreads();

  {
    int a = tid >> 4, e = tid & 15;
    const bf16* aw = actor_w + (size_t)a * 256 + e * 16;
    const float* zr = qs + e * 16;
    float acc = 0.f;
#pragma unroll
    for (int hh = 0; hh < 16; hh++) acc += (float)aw[hh] * zr[hh];
    sA[tid] = acc;
  }
  __syncthreads();
  if (tid < 16) {
    float lg = (float)actor_b[tid];
#pragma unroll
    for (int e = 0; e < 16; e++) lg += sA[tid * 16 + e];
    float mx = lg;
#pragma unroll
    for (int m = 8; m > 0; m >>= 1) mx = fmaxf(mx, __shfl_xor(mx, m, 16));
    float ex = __expf(lg - mx);
    float sm = ex;
#pragma unroll
    for (int m = 8; m > 0; m >>= 1) sm += __shfl_xor(sm, m, 16);
    al[tid] = ex / sm;
  }
  __syncthreads();

  size_t rowoff = (size_t)(t * 64 + n) * 339;
  if (flags[1]) {
    float* ob = (float*)out_raw + rowoff;
    if (tid == 0) {
      ob[0] = (float)a_idx[t * 64 + n];
      ob[1] = (float)p;
      ob[2] = scal[0];
    }
    ob[3 + tid] = hs[tid];
    if (tid < 16) ob[259 + tid] = al[tid];
    if (tid < 64) ob[275 + tid] = pl[tid];
  } else {
    bf16* ob = (bf16*)out_raw + rowoff;
    if (tid == 0) {
      ob[0] = (bf16)(float)a_idx[t * 64 + n];
      ob[1] = (bf16)(float)p;
      ob[2] = (bf16)scal[0];
    }
    ob[3 + tid] = (bf16)hs[tid];
    if (tid < 16) ob[259 + tid] = (bf16)al[tid];
    if (tid < 64) ob[275 + tid] = (bf16)pl[tid];
  }
}

// =====================================================================
extern "C" void kernel_launch(void* const* d_in, const int* in_sizes, int n_in,
                              void* d_out, int out_size, void* d_ws, size_t ws_size,
                              hipStream_t stream) {
  (void)in_sizes; (void)n_in; (void)out_size; (void)ws_size;
  const void* condition = d_in[0];
  const int* lines      = (const int*)d_in[1];
  const int* a_idx      = (const int*)d_in[2];
  const int* p_idx      = (const int*)d_in[3];

  char* ws = (char*)d_ws;
  bf16* xi            = (bf16*)(ws + XI_OFF);
  unsigned char* K1c  = (unsigned char*)(ws + K1_OFF);
  float* gi           = (float*)(ws + GI_OFF);
  float* hdec         = (float*)(ws + HD_OFF);
  int* slot_map       = (int*)(ws + SLOT_OFF);
  int* flags          = (int*)(ws + FLG_OFF);
  bf16* cw            = (bf16*)(ws + CW_OFF);
  unsigned char* wh8  = (unsigned char*)(ws + WH8_OFF);

  static const int src_idx[26] = {4, 5, 6, 7, 8, 9, 10, 11, 12, 13, 14, 15, 16,
                                  17, 18, 19, 20, 21, 22, 23, 24, 25, 26, 27, 28, 29};
  static const int offs[26] = {o_embed, o_aemb, o_wi_f, o_wh_f, o_bi_f, o_bh_f,
                               o_wi_b, o_wh_b, o_bi_b, o_bh_b, o_f_w1, o_f_b1,
                               o_f_w2, o_f_b2, o_cell_wi, o_cell_wh, o_cell_bi,
                               o_cell_bh, o_critic_w, o_critic_b, o_pointer_w,
                               o_pointer_b, o_actor_w, o_actor_b, o_query_w, o_query_b};
  static const int cnts[26] = {32768, 4096, 196608, 196608, 768, 768,
                               196608, 196608, 768, 768, 81920, 256,
                               65536, 256, 196608, 196608, 768,
                               768, 256, 1, 16384, 64, 4096, 16, 65536, 256};
  RepackArgs ra;
  int total = 0;
  for (int i = 0; i < 26; i++) {
    ra.src[i] = d_in[src_idx[i]];
    ra.off[i] = offs[i];
    ra.cnt[i] = cnts[i];
    total += cnts[i];
  }
  int nchunks = (total + 2047) / 2048;

  k_detect<<<1, 256, 0, stream>>>((const uint32_t*)condition, (const uint32_t*)d_in[4], flags);
  k_repack<<<nchunks, 256, 0, stream>>>(ra, flags, cw);
  k_repack8<<<384, 1024, 0, stream>>>(cw, wh8);
  k_slot<<<1, 256, 0, stream>>>(p_idx, slot_map);
  k_xi<<<256, 256, 0, stream>>>(lines, cw, xi);
  k_bigru<<<256, 1024, 0, stream>>>(cw, wh8, xi, slot_map, K1c);
  k_dec_gi<<<64, 256, 0, stream>>>(condition, flags, a_idx, cw, gi);
  k_dec_h<<<4, 512, 0, stream>>>(cw, gi, hdec);
  k_dec_out<<<2048, 256, 0, stream>>>(hdec, K1c, slot_map, flags, a_idx, p_idx, cw, d_out);
}

// Round 6
// 429.234 us; speedup vs baseline: 3.4089x; 1.7535x over previous
//
#include <hip/hip_runtime.h>
#include <hip/hip_bf16.h>
#include <cstddef>
#include <cstdint>

// ---------- types ----------
typedef __bf16 bf16;
typedef bf16 bf16x8 __attribute__((ext_vector_type(8)));
typedef float f32x4 __attribute__((ext_vector_type(4)));

#define DEV static __device__ __forceinline__

DEV f32x4 mfma_bf16(bf16x8 a, bf16x8 b, f32x4 c) {
  return __builtin_amdgcn_mfma_f32_16x16x32_bf16(a, b, c, 0, 0, 0);
}
DEV f32x4 mfma_fp8(long a, long b, f32x4 c) {
  return __builtin_amdgcn_mfma_f32_16x16x32_fp8_fp8(a, b, c, 0, 0, 0);
}

DEV float sigmoid_f(float x) { return 1.0f / (1.0f + __expf(-x)); }
DEV float tanh_f(float x) {
  float ax = fabsf(x);
  float e = __expf(-2.0f * ax);
  float t = 1.0f - 2.0f * e / (1.0f + e);
  return copysignf(t, x);
}
DEV unsigned char fp8_of(float x) {
  return (unsigned char)(__builtin_amdgcn_cvt_pk_fp8_f32(x, x, 0, false) & 0xFF);
}

// ---------- problem constants: T=32,N=64,C=64,L=64,H=256,NA=16,NL=128 ----------
static constexpr int H_ = 256;

// ---------- canonical bf16 weight region: element offsets ----------
static constexpr int o_embed = 0;
static constexpr int o_aemb = 32768;
static constexpr int o_wi_f = 36864;
static constexpr int o_wh_f = 233472;
static constexpr int o_bi_f = 430080;
static constexpr int o_bh_f = 430848;
static constexpr int o_wi_b = 431616;
static constexpr int o_wh_b = 628224;
static constexpr int o_bi_b = 824832;
static constexpr int o_bh_b = 825600;
static constexpr int o_f_w1 = 826368;
static constexpr int o_f_b1 = 908288;
static constexpr int o_f_w2 = 908544;
static constexpr int o_f_b2 = 974080;
static constexpr int o_cell_wi = 974336;
static constexpr int o_cell_wh = 1170944;
static constexpr int o_cell_bi = 1367552;
static constexpr int o_cell_bh = 1368320;
static constexpr int o_critic_w = 1369088;
static constexpr int o_critic_b = 1369344;
static constexpr int o_pointer_w = 1369360;
static constexpr int o_pointer_b = 1385744;
static constexpr int o_actor_w = 1385808;
static constexpr int o_actor_b = 1389904;
static constexpr int o_query_w = 1389920;
static constexpr int o_query_b = 1455456;
static constexpr int CW_TOTAL = 1455712;
static constexpr int WH8_TOTAL = 393216;  // fp8 [2][768][256]
static constexpr int PREP_TOTAL = CW_TOTAL + WH8_TOTAL;  // 1,848,928
static constexpr int PREP_WGS = (PREP_TOTAL + 2047) / 2048;  // 903

// ---------- workspace layout (bytes), ~91.4 MB ----------
static constexpr size_t XI_OFF = 0;
static constexpr size_t XI_BYTES = 2ull * 64 * 64 * 768 * 2;      // 12.58 MB
static constexpr size_t QS_OFF = XI_OFF;                           // reuse (xi dead when heads runs)
static constexpr size_t K1_OFF = XI_OFF + XI_BYTES;
static constexpr size_t K1_BYTES = 64ull * 32 * 128 * 256;        // 67.1 MB
static constexpr size_t GI_OFF = K1_OFF + K1_BYTES;
static constexpr size_t GI_BYTES = 32ull * 64 * 768 * 4;
static constexpr size_t HD_OFF = GI_OFF + GI_BYTES;
static constexpr size_t HD_BYTES = 32ull * 64 * 256 * 4;
static constexpr size_t SLOT_OFF = HD_OFF + HD_BYTES;
static constexpr size_t SLOT_BYTES = 64ull * 64 * 4;
static constexpr size_t FLG_OFF = SLOT_OFF + SLOT_BYTES;
static constexpr size_t FLG_BYTES = 256;
static constexpr size_t WL_OFF = FLG_OFF + FLG_BYTES;             // hdr int[8] @ +0, u16 ent[8][512] @ +64
static constexpr size_t WL_BYTES = 8448;
static constexpr size_t CW_OFF = WL_OFF + WL_BYTES;
static constexpr size_t CW_BYTES = (size_t)CW_TOTAL * 2;
static constexpr size_t WH8_OFF = ((CW_OFF + CW_BYTES + 255) / 256) * 256;

struct PrepArgs {
  const void* src[26];
  int off[26];
  int cnt[26];
};

// =====================================================================
// P: prep — per-WG local dtype detect, repack cw + wh8; WG 903 builds
// slot_map + per-XCD work list (used (n,roll) pairs, roll-sorted).
// =====================================================================
__global__ __launch_bounds__(256)
void k_prep(PrepArgs pa, const uint32_t* __restrict__ cond, const uint32_t* __restrict__ emb,
            const void* __restrict__ whf_src, const void* __restrict__ whb_src,
            const int* __restrict__ p_idx, int* __restrict__ flags,
            bf16* __restrict__ cw, unsigned char* __restrict__ wh8,
            int* __restrict__ slot_map, int* __restrict__ wl) {
  int bx = blockIdx.x;
  int tid = threadIdx.x;
  __shared__ int votes[256];

  // local weights-dtype detect (512 samples of embed)
  int c1 = 0;
  {
    uint32_t w0 = emb[tid * 2], w1 = emb[tid * 2 + 1];
    int e0 = (int)((w0 >> 7) & 0xFF), e1 = (int)((w1 >> 7) & 0xFF);
    c1 += (e0 >= 96 && e0 <= 130) ? 1 : 0;
    c1 += (e1 >= 96 && e1 <= 130) ? 1 : 0;
  }
  votes[tid] = c1;
  __syncthreads();
  __shared__ int f32w_s;
  if (tid == 0) {
    int s = 0;
    for (int i = 0; i < 256; i++) s += votes[i];
    f32w_s = (s < 256) ? 1 : 0;
  }
  __syncthreads();
  bool f32w = f32w_s != 0;

  if (bx == 0) {  // condition-dtype detect + publish flags
    __syncthreads();
    int c0 = 0;
    {
      uint32_t w0 = cond[tid * 2], w1 = cond[tid * 2 + 1];
      int e0 = (int)((w0 >> 7) & 0xFF), e1 = (int)((w1 >> 7) & 0xFF);
      c0 += (e0 >= 96 && e0 <= 130) ? 1 : 0;
      c0 += (e1 >= 96 && e1 <= 130) ? 1 : 0;
    }
    votes[tid] = c0;
    __syncthreads();
    if (tid == 0) {
      int s = 0;
      for (int i = 0; i < 256; i++) s += votes[i];
      flags[0] = (s < 256) ? 1 : 0;
      flags[1] = f32w ? 1 : 0;
    }
  }

  if (bx < PREP_WGS) {  // repack slice
    int gidx = bx * 2048 + tid;
    for (int e = 0; e < 8; e++, gidx += 256) {
      if (gidx >= PREP_TOTAL) break;
      if (gidx < CW_TOTAL) {
        int rem = gidx, s = 0;
        while (s < 26 && rem >= pa.cnt[s]) { rem -= pa.cnt[s]; s++; }
        if (s < 26) {
          float v = f32w ? ((const float*)pa.src[s])[rem]
                         : (float)((const bf16*)pa.src[s])[rem];
          cw[pa.off[s] + rem] = (bf16)v;
        }
      } else {
        int i = gidx - CW_TOTAL;
        const void* src = (i < 196608) ? whf_src : whb_src;
        int k = (i < 196608) ? i : i - 196608;
        float v = f32w ? ((const float*)src)[k] : (float)((const bf16*)src)[k];
        wh8[i] = fp8_of(v);
      }
    }
    return;
  }

  // ---- bx == PREP_WGS: slot_map + worklist ----
  __shared__ int pbuf[2048];
  __shared__ signed char sm[4096];
  __shared__ unsigned short entL[8 * 512];
  __shared__ int cntL[8];
  for (int i = tid; i < 2048; i += 256) pbuf[i] = p_idx[i];
  for (int i = tid; i < 4096; i += 256) sm[i] = -1;
  __syncthreads();
  if (tid < 64) {
    int n = tid, cnt = 0;
    for (int t = 0; t < 32; t++) {
      int p = pbuf[t * 64 + n];
      if (sm[n * 64 + p] < 0) sm[n * 64 + p] = (signed char)(cnt++);
    }
  }
  __syncthreads();
  for (int i = tid; i < 4096; i += 256) slot_map[i] = (int)sm[i];
  if (tid < 8) {
    int xcd = tid, cnt = 0;
    for (int roll = xcd * 8; roll < xcd * 8 + 8; roll++)
      for (int n = 0; n < 64; n++)
        if (sm[n * 64 + roll] >= 0) entL[xcd * 512 + (cnt++)] = (unsigned short)(n | (roll << 8));
    unsigned short pad = (unsigned short)((xcd * 8) << 8);  // (n=0, roll=8*xcd)
    while (cnt & 15) entL[xcd * 512 + (cnt++)] = pad;
    cntL[xcd] = cnt;
  }
  __syncthreads();
  if (tid < 8) wl[tid] = cntL[tid] >> 4;  // nchunks
  unsigned short* we = (unsigned short*)((char*)wl + 64);
  for (int i = tid; i < 8 * 512; i += 256) we[i] = entL[i];
}

// =====================================================================
// XG: fused k_xi (bx<256) + k_dec_gi (bx>=256). 256 thr.
// =====================================================================
__global__ __launch_bounds__(256)
void k_xi_gi(const int* __restrict__ lines, const bf16* __restrict__ cw,
             const void* __restrict__ cond_raw, const int* __restrict__ flags,
             const int* __restrict__ a_idx, bf16* __restrict__ xi,
             float* __restrict__ gi) {
  int bx = blockIdx.x;
  int tid = threadIdx.x;
  int w = tid >> 6, l = tid & 63, quad = l >> 4, l15 = l & 15;
  __shared__ __attribute__((aligned(16))) bf16 s_a[32 * 328];  // xi: xs(32*264) / gi: obs
  __shared__ __attribute__((aligned(16))) bf16 s_b[32 * 264];  // gi: xf1

  if (bx < 256) {  // ---- xi GEMM ----
    int dir = bx & 1, rb = bx >> 1;
    const bf16* embed = cw + o_embed;
    const bf16* wi = cw + (dir ? o_wi_b : o_wi_f);
    const bf16* bi = cw + (dir ? o_bi_b : o_bi_f);
    bf16* xs = s_a;
    {
      int row = tid >> 3, seg = tid & 7;
      int grow = rb * 32 + row;
      int u = grow >> 6, n = grow & 63;
      int line = lines[n * 64 + u];
      const bf16* src = embed + (size_t)line * H_ + seg * 32;
      bf16* dst = xs + row * 264 + seg * 32;
#pragma unroll
      for (int e = 0; e < 4; e++) *(bf16x8*)(dst + e * 8) = *(const bf16x8*)(src + e * 8);
    }
    __syncthreads();
    f32x4 acc[2][12];
#pragma unroll
    for (int mt = 0; mt < 2; mt++)
#pragma unroll
      for (int nt = 0; nt < 12; nt++) acc[mt][nt] = f32x4{0.f, 0.f, 0.f, 0.f};
#pragma unroll
    for (int ks = 0; ks < 8; ks++) {
      int koff = ks * 32 + quad * 8;
      bf16x8 a0 = *(const bf16x8*)(xs + l15 * 264 + koff);
      bf16x8 a1 = *(const bf16x8*)(xs + (l15 + 16) * 264 + koff);
#pragma unroll
      for (int nt = 0; nt < 12; nt++) {
        int g = (w * 12 + nt) * 16 + l15;
        bf16x8 b = *(const bf16x8*)(wi + (size_t)g * H_ + koff);
        acc[0][nt] = mfma_bf16(a0, b, acc[0][nt]);
        acc[1][nt] = mfma_bf16(a1, b, acc[1][nt]);
      }
    }
    size_t base = (size_t)dir * 4096 * 768;
#pragma unroll
    for (int nt = 0; nt < 12; nt++) {
      int g = (w * 12 + nt) * 16 + l15;
      float bias = (float)bi[g];
#pragma unroll
      for (int mt = 0; mt < 2; mt++)
#pragma unroll
        for (int r = 0; r < 4; r++) {
          int m = mt * 16 + quad * 4 + r;
          xi[base + (size_t)(rb * 32 + m) * 768 + g] = (bf16)(acc[mt][nt][r] + bias);
        }
    }
    return;
  }

  // ---- gi MLP chain ----
  int rb = bx - 256;
  const bf16* aemb = cw + o_aemb;
  const bf16* f_w1 = cw + o_f_w1;
  const bf16* f_b1 = cw + o_f_b1;
  const bf16* f_w2 = cw + o_f_w2;
  const bf16* f_b2 = cw + o_f_b2;
  const bf16* cell_wi = cw + o_cell_wi;
  const bf16* cell_bi = cw + o_cell_bi;
  bool cf32 = flags[0] != 0;
  bf16* obs = s_a;
  bf16* xf1 = s_b;

  for (int e = tid; e < 32 * 320; e += 256) {
    int row = e / 320, col = e - row * 320;
    int grow = rb * 32 + row;
    int t = grow >> 6, n = grow & 63;
    float v;
    if (col < 64) {
      v = cf32 ? ((const float*)cond_raw)[(size_t)grow * 64 + col]
               : (float)((const bf16*)cond_raw)[(size_t)grow * 64 + col];
    } else {
      int ap = (t == 0) ? 0 : a_idx[(t - 1) * 64 + n];
      v = (float)aemb[ap * 256 + (col - 64)];
    }
    obs[row * 328 + col] = (bf16)v;
  }
  __syncthreads();
  {  // GEMM1 K=320 -> relu -> xf1
    f32x4 acc[2][4];
#pragma unroll
    for (int mt = 0; mt < 2; mt++)
#pragma unroll
      for (int nt = 0; nt < 4; nt++) acc[mt][nt] = f32x4{0.f, 0.f, 0.f, 0.f};
#pragma unroll
    for (int ks = 0; ks < 10; ks++) {
      int koff = ks * 32 + quad * 8;
      bf16x8 a0 = *(const bf16x8*)(obs + l15 * 328 + koff);
      bf16x8 a1 = *(const bf16x8*)(obs + (l15 + 16) * 328 + koff);
#pragma unroll
      for (int nt = 0; nt < 4; nt++) {
        int g = (w * 4 + nt) * 16 + l15;
        bf16x8 b = *(const bf16x8*)(f_w1 + (size_t)g * 320 + koff);
        acc[0][nt] = mfma_bf16(a0, b, acc[0][nt]);
        acc[1][nt] = mfma_bf16(a1, b, acc[1][nt]);
      }
    }
#pragma unroll
    for (int nt = 0; nt < 4; nt++) {
      int g = (w * 4 + nt) * 16 + l15;
      float bias = (float)f_b1[g];
#pragma unroll
      for (int mt = 0; mt < 2; mt++)
#pragma unroll
        for (int r = 0; r < 4; r++) {
          int m = mt * 16 + quad * 4 + r;
          xf1[m * 264 + g] = (bf16)fmaxf(acc[mt][nt][r] + bias, 0.f);
        }
    }
  }
  __syncthreads();
  bf16* xf2 = obs;
  {  // GEMM2 K=256 -> relu -> xf2
    f32x4 acc[2][4];
#pragma unroll
    for (int mt = 0; mt < 2; mt++)
#pragma unroll
      for (int nt = 0; nt < 4; nt++) acc[mt][nt] = f32x4{0.f, 0.f, 0.f, 0.f};
#pragma unroll
    for (int ks = 0; ks < 8; ks++) {
      int koff = ks * 32 + quad * 8;
      bf16x8 a0 = *(const bf16x8*)(xf1 + l15 * 264 + koff);
      bf16x8 a1 = *(const bf16x8*)(xf1 + (l15 + 16) * 264 + koff);
#pragma unroll
      for (int nt = 0; nt < 4; nt++) {
        int g = (w * 4 + nt) * 16 + l15;
        bf16x8 b = *(const bf16x8*)(f_w2 + (size_t)g * 256 + koff);
        acc[0][nt] = mfma_bf16(a0, b, acc[0][nt]);
        acc[1][nt] = mfma_bf16(a1, b, acc[1][nt]);
      }
    }
#pragma unroll
    for (int nt = 0; nt < 4; nt++) {
      int g = (w * 4 + nt) * 16 + l15;
      float bias = (float)f_b2[g];
#pragma unroll
      for (int mt = 0; mt < 2; mt++)
#pragma unroll
        for (int r = 0; r < 4; r++) {
          int m = mt * 16 + quad * 4 + r;
          xf2[m * 264 + g] = (bf16)fmaxf(acc[mt][nt][r] + bias, 0.f);
        }
    }
  }
  __syncthreads();
  {  // GEMM3 -> gi f32
    f32x4 acc[2][12];
#pragma unroll
    for (int mt = 0; mt < 2; mt++)
#pragma unroll
      for (int nt = 0; nt < 12; nt++) acc[mt][nt] = f32x4{0.f, 0.f, 0.f, 0.f};
#pragma unroll
    for (int ks = 0; ks < 8; ks++) {
      int koff = ks * 32 + quad * 8;
      bf16x8 a0 = *(const bf16x8*)(xf2 + l15 * 264 + koff);
      bf16x8 a1 = *(const bf16x8*)(xf2 + (l15 + 16) * 264 + koff);
#pragma unroll
      for (int nt = 0; nt < 12; nt++) {
        int g = (w * 12 + nt) * 16 + l15;
        bf16x8 b = *(const bf16x8*)(cell_wi + (size_t)g * 256 + koff);
        acc[0][nt] = mfma_bf16(a0, b, acc[0][nt]);
        acc[1][nt] = mfma_bf16(a1, b, acc[1][nt]);
      }
    }
#pragma unroll
    for (int nt = 0; nt < 12; nt++) {
      int g = (w * 12 + nt) * 16 + l15;
      float bias = (float)cell_bi[g];
#pragma unroll
      for (int mt = 0; mt < 2; mt++)
#pragma unroll
        for (int r = 0; r < 4; r++) {
          int m = mt * 16 + quad * 4 + r;
          gi[(size_t)(rb * 32 + m) * 768 + g] = acc[mt][nt][r] + bias;
        }
    }
  }
}

// =====================================================================
// M: fused bigru (work-list, bx<512) + decoder GRU (bx>=512). 1024 thr.
// bigru: xcd=bx&7, dir=(bx>>3)&1, slot=bx>>4; chunk of 16 (n,roll) rows.
// Wave w owns cols [16w,16w+16) x 3 gates; M=16; fp8 wh + fp8 h.
// =====================================================================
__global__ __launch_bounds__(1024)
void k_main(const bf16* __restrict__ cw, const unsigned char* __restrict__ wh8,
            const bf16* __restrict__ xi, const int* __restrict__ slot_map,
            const int* __restrict__ wl, const float* __restrict__ gi,
            unsigned char* __restrict__ K1c, float* __restrict__ hdec) {
  int bx = blockIdx.x;
  int tid = threadIdx.x;
  int w = tid >> 6, l = tid & 63, quad = l >> 4, l15 = l & 15;
  int c = w * 16 + l15;
  __shared__ __attribute__((aligned(16))) unsigned char smem[2][16 * 264 * 2];

  if (bx < 512) {  // ---------------- bigru ----------------
    int xcd = bx & 7, dir = (bx >> 3) & 1, slot = bx >> 4;
    if (slot >= wl[xcd]) return;
    const unsigned short* we = (const unsigned short*)((const char*)wl + 64) + xcd * 512 + slot * 16;
    const unsigned char* whd = wh8 + (size_t)dir * 196608;
    const bf16* bh = cw + (dir ? o_bh_b : o_bh_f);

    unsigned char (*hb)[16 * 264 * 2] = smem;  // fp8, use first 4224 B of each
    for (int idx = tid; idx < 16 * 264; idx += 1024) hb[0][idx] = 0;

    // compute rows (quad*4+r)
    int rollv[4], nbase[4];
#pragma unroll
    for (int r = 0; r < 4; r++) {
      int e = we[quad * 4 + r];
      rollv[r] = e >> 8;
      nbase[r] = (e & 255) * 768;
    }
    // copy row
    int crow = tid >> 6, cseg = tid & 63;
    int ec = we[crow];
    int n_c = ec & 255, roll_c = ec >> 8;
    int kslot = slot_map[n_c * 64 + roll_c];
    unsigned char* dstb = K1c + ((size_t)n_c * 32 + (kslot < 0 ? 0 : kslot)) * 32768 + cseg * 4;

    float hreg[4] = {0.f, 0.f, 0.f, 0.f};
    float bhv[3];
    const unsigned char* bp[3];
#pragma unroll
    for (int g = 0; g < 3; g++) {
      int grow = g * 256 + c;
      bhv[g] = (float)bh[grow];
      bp[g] = whd + (size_t)grow * 256 + quad * 8;
    }
    const bf16* xid = xi + (size_t)dir * 4096 * 768;
    __syncthreads();

    int cur = 0;
    for (int t = 0; t < 64; t++) {
      int j = dir ? (63 - t) : t;
      float xiv[3][4];
#pragma unroll
      for (int r = 0; r < 4; r++) {
        int u = dir ? ((63 - t - rollv[r]) & 63) : ((t - rollv[r]) & 63);
        const bf16* xr = xid + u * 49152 + nbase[r] + c;
#pragma unroll
        for (int g = 0; g < 3; g++) xiv[g][r] = (float)xr[g * 256];
      }
      f32x4 acc[3];
#pragma unroll
      for (int g = 0; g < 3; g++) acc[g] = f32x4{0.f, 0.f, 0.f, 0.f};
#pragma unroll
      for (int ks = 0; ks < 8; ks++) {
        int ko = ks * 32 + quad * 8;
        long a0 = *(const long*)(hb[cur] + l15 * 264 + ko);
#pragma unroll
        for (int g = 0; g < 3; g++) {
          long b = *(const long*)(bp[g] + ks * 32);
          acc[g] = mfma_fp8(a0, b, acc[g]);
        }
      }
      int nxt = cur ^ 1;
#pragma unroll
      for (int r = 0; r < 4; r++) {
        float rg = sigmoid_f(xiv[0][r] + acc[0][r] + bhv[0]);
        float zg = sigmoid_f(xiv[1][r] + acc[1][r] + bhv[1]);
        float ng = tanh_f(xiv[2][r] + rg * (acc[2][r] + bhv[2]));
        hreg[r] = (1.f - zg) * ng + zg * hreg[r];
        hb[nxt][(quad * 4 + r) * 264 + c] = fp8_of(hreg[r]);
      }
      __syncthreads();
      if (kslot >= 0) {
        *(uint32_t*)(dstb + (size_t)(j * 2 + dir) * 256) =
            *(const uint32_t*)(hb[nxt] + crow * 264 + cseg * 4);
      }
      cur = nxt;
    }
    return;
  }

  // ---------------- decoder GRU cell (4 WGs, M=16 n-rows) ----------------
  int nq = bx - 512;
  const bf16* wh = cw + o_cell_wh;
  const bf16* bh = cw + o_cell_bh;
  bf16 (*hb)[16 * 264] = (bf16(*)[16 * 264])smem;  // bf16 16x264 x2
  for (int idx = tid; idx < 16 * 264; idx += 1024) hb[0][idx] = (bf16)0.f;

  float hreg[4] = {0.f, 0.f, 0.f, 0.f};
  float bhv[3];
  const bf16* bp[3];
#pragma unroll
  for (int g = 0; g < 3; g++) {
    int grow = g * 256 + c;
    bhv[g] = (float)bh[grow];
    bp[g] = wh + (size_t)grow * 256 + quad * 8;
  }
  __syncthreads();

  int cur = 0;
  for (int t = 0; t < 32; t++) {
    const float* gr = gi + ((size_t)t * 64 + nq * 16) * 768;
    float giv[3][4];
#pragma unroll
    for (int r = 0; r < 4; r++)
#pragma unroll
      for (int g = 0; g < 3; g++)
        giv[g][r] = gr[(quad * 4 + r) * 768 + g * 256 + c];

    f32x4 acc[3];
#pragma unroll
    for (int g = 0; g < 3; g++) acc[g] = f32x4{0.f, 0.f, 0.f, 0.f};
#pragma unroll
    for (int ks = 0; ks < 8; ks++) {
      int ko = ks * 32 + quad * 8;
      bf16x8 a0 = *(const bf16x8*)(hb[cur] + l15 * 264 + ko);
#pragma unroll
      for (int g = 0; g < 3; g++) {
        bf16x8 b = *(const bf16x8*)(bp[g] + ks * 32);
        acc[g] = mfma_bf16(a0, b, acc[g]);
      }
    }
    int nxt = cur ^ 1;
#pragma unroll
    for (int r = 0; r < 4; r++) {
      float rg = sigmoid_f(giv[0][r] + acc[0][r] + bhv[0]);
      float zg = sigmoid_f(giv[1][r] + acc[1][r] + bhv[1]);
      float ng = tanh_f(giv[2][r] + rg * (acc[2][r] + bhv[2]));
      float hnew = (1.f - zg) * ng + zg * hreg[r];
      hreg[r] = hnew;
      hb[nxt][(quad * 4 + r) * 264 + c] = (bf16)hnew;
      hdec[((size_t)t * 64 + nq * 16 + quad * 4 + r) * 256 + c] = hnew;
    }
    __syncthreads();
    cur = nxt;
  }
}

// =====================================================================
// H: batched heads — q GEMM (-> qs_ws), pointer GEMM + softmax, critic,
// and out writes for a, p, v, h, p_probs. 64 WGs x 256 thr, 32 rows each.
// =====================================================================
__global__ __launch_bounds__(256)
void k_heads(const float* __restrict__ hdec, const int* __restrict__ flags,
             const int* __restrict__ a_idx, const int* __restrict__ p_idx,
             const bf16* __restrict__ cw, float* __restrict__ qs_ws,
             void* __restrict__ out_raw) {
  int rb = blockIdx.x;
  int tid = threadIdx.x;
  int w = tid >> 6, l = tid & 63, quad = l >> 4, l15 = l & 15;
  const bf16* query_w = cw + o_query_w;
  const bf16* query_b = cw + o_query_b;
  const bf16* pointer_w = cw + o_pointer_w;
  const bf16* pointer_b = cw + o_pointer_b;
  const bf16* critic_w = cw + o_critic_w;
  const bf16* critic_b = cw + o_critic_b;

  __shared__ __attribute__((aligned(16))) bf16 hsb[32 * 264];
  __shared__ float pls[32 * 66];
  __shared__ float vred[32 * 8];

  for (int idx = tid; idx < 32 * 256; idx += 256) {
    int row = idx >> 8, col = idx & 255;
    hsb[row * 264 + col] = (bf16)hdec[(size_t)(rb * 32 + row) * 256 + col];
  }
  __syncthreads();

  {  // q GEMM: 256 out cols
    f32x4 acc[2][4];
#pragma unroll
    for (int mt = 0; mt < 2; mt++)
#pragma unroll
      for (int nt = 0; nt < 4; nt++) acc[mt][nt] = f32x4{0.f, 0.f, 0.f, 0.f};
#pragma unroll
    for (int ks = 0; ks < 8; ks++) {
      int koff = ks * 32 + quad * 8;
      bf16x8 a0 = *(const bf16x8*)(hsb + l15 * 264 + koff);
      bf16x8 a1 = *(const bf16x8*)(hsb + (l15 + 16) * 264 + koff);
#pragma unroll
      for (int nt = 0; nt < 4; nt++) {
        int g = (w * 4 + nt) * 16 + l15;
        bf16x8 b = *(const bf16x8*)(query_w + (size_t)g * 256 + koff);
        acc[0][nt] = mfma_bf16(a0, b, acc[0][nt]);
        acc[1][nt] = mfma_bf16(a1, b, acc[1][nt]);
      }
    }
#pragma unroll
    for (int nt = 0; nt < 4; nt++) {
      int g = (w * 4 + nt) * 16 + l15;
      float bias = (float)query_b[g];
#pragma unroll
      for (int mt = 0; mt < 2; mt++)
#pragma unroll
        for (int r = 0; r < 4; r++) {
          int m = mt * 16 + quad * 4 + r;
          qs_ws[(size_t)(rb * 32 + m) * 256 + g] = acc[mt][nt][r] + bias;
        }
    }
  }
  {  // pointer GEMM: 64 out cols -> pls
    f32x4 acc[2];
    acc[0] = f32x4{0.f, 0.f, 0.f, 0.f};
    acc[1] = f32x4{0.f, 0.f, 0.f, 0.f};
    int g = w * 16 + l15;
#pragma unroll
    for (int ks = 0; ks < 8; ks++) {
      int koff = ks * 32 + quad * 8;
      bf16x8 a0 = *(const bf16x8*)(hsb + l15 * 264 + koff);
      bf16x8 a1 = *(const bf16x8*)(hsb + (l15 + 16) * 264 + koff);
      bf16x8 b = *(const bf16x8*)(pointer_w + (size_t)g * 256 + koff);
      acc[0] = mfma_bf16(a0, b, acc[0]);
      acc[1] = mfma_bf16(a1, b, acc[1]);
    }
    float bias = (float)pointer_b[g];
#pragma unroll
    for (int mt = 0; mt < 2; mt++)
#pragma unroll
      for (int r = 0; r < 4; r++) {
        int m = mt * 16 + quad * 4 + r;
        pls[m * 66 + g] = acc[mt][r] + bias;
      }
  }
  {  // critic partials
    int row = tid >> 3, seg = tid & 7;
    float acc = 0.f;
#pragma unroll
    for (int k = 0; k < 32; k++)
      acc += (float)hsb[row * 264 + seg * 32 + k] * (float)critic_w[seg * 32 + k];
    vred[row * 8 + seg] = acc;
  }
  __syncthreads();

  if (tid < 32) {  // pointer softmax (in-place -> probs) + v
    float mx = -1e30f;
    for (int k = 0; k < 64; k++) mx = fmaxf(mx, pls[tid * 66 + k]);
    float sm = 0.f;
    for (int k = 0; k < 64; k++) {
      float e = __expf(pls[tid * 66 + k] - mx);
      pls[tid * 66 + k] = e;
      sm += e;
    }
    float inv = 1.f / sm;
    for (int k = 0; k < 64; k++) pls[tid * 66 + k] *= inv;
    float v = (float)critic_b[0];
    for (int s = 0; s < 8; s++) v += vred[tid * 8 + s];
    vred[tid * 8] = v;  // stash
  }
  __syncthreads();

  bool f32o = flags[1] != 0;
  if (f32o) {
    float* ob = (float*)out_raw;
    if (tid < 32) {
      int grow = rb * 32 + tid;
      ob[(size_t)grow * 339 + 0] = (float)a_idx[grow];
      ob[(size_t)grow * 339 + 1] = (float)p_idx[grow];
      ob[(size_t)grow * 339 + 2] = vred[tid * 8];
    }
    for (int idx = tid; idx < 32 * 256; idx += 256) {
      int row = idx >> 8, col = idx & 255;
      int grow = rb * 32 + row;
      ob[(size_t)grow * 339 + 3 + col] = hdec[(size_t)grow * 256 + col];
    }
    for (int idx = tid; idx < 32 * 64; idx += 256) {
      int row = idx >> 6, col = idx & 63;
      ob[(size_t)(rb * 32 + row) * 339 + 275 + col] = pls[row * 66 + col];
    }
  } else {
    bf16* ob = (bf16*)out_raw;
    if (tid < 32) {
      int grow = rb * 32 + tid;
      ob[(size_t)grow * 339 + 0] = (bf16)(float)a_idx[grow];
      ob[(size_t)grow * 339 + 1] = (bf16)(float)p_idx[grow];
      ob[(size_t)grow * 339 + 2] = (bf16)vred[tid * 8];
    }
    for (int idx = tid; idx < 32 * 256; idx += 256) {
      int row = idx >> 8, col = idx & 255;
      int grow = rb * 32 + row;
      ob[(size_t)grow * 339 + 3 + col] = (bf16)hdec[(size_t)grow * 256 + col];
    }
    for (int idx = tid; idx < 32 * 64; idx += 256) {
      int row = idx >> 6, col = idx & 63;
      ob[(size_t)(rb * 32 + row) * 339 + 275 + col] = (bf16)pls[row * 66 + col];
    }
  }
}

// =====================================================================
// A: attention per (t,n): l = K q, zz = K^T l, actor head + softmax.
// 2048 WGs x 256 thr.
// =====================================================================
__global__ __launch_bounds__(256)
void k_attn(const float* __restrict__ qs_ws, const unsigned char* __restrict__ K1c,
            const int* __restrict__ slot_map, const int* __restrict__ flags,
            const int* __restrict__ p_idx, const bf16* __restrict__ cw,
            void* __restrict__ out_raw) {
  int bx = blockIdx.x;
  int t = bx >> 6, n = bx & 63;
  int tid = threadIdx.x;
  const bf16* actor_w = cw + o_actor_w;
  const bf16* actor_b = cw + o_actor_b;

  __shared__ float qs[256], ls[256], sA[256], al[16];
  __shared__ __attribute__((aligned(16))) unsigned char ksb[128 * 264];

  qs[tid] = qs_ws[(size_t)(t * 64 + n) * 256 + tid];
  int p = p_idx[t * 64 + n];
  int slot = slot_map[n * 64 + p];
  {
    const uint32_t* kg = (const uint32_t*)(K1c + ((size_t)n * 32 + slot) * 32768);
#pragma unroll
    for (int e = 0; e < 8; e++) {
      int flat = (e * 256 + tid) * 16;
      int kk = flat >> 8, col = flat & 255;
      uint32_t w0 = kg[(flat >> 2) + 0], w1 = kg[(flat >> 2) + 1];
      uint32_t w2 = kg[(flat >> 2) + 2], w3 = kg[(flat >> 2) + 3];
      uint32_t* d0 = (uint32_t*)(ksb + kk * 264 + col);
      d0[0] = w0; d0[1] = w1; d0[2] = w2; d0[3] = w3;
    }
  }
  __syncthreads();

  {  // l partials
    int kk = tid & 127, hc = tid >> 7;
    const uint32_t* kr = (const uint32_t*)(ksb + kk * 264 + hc * 128);
    const float* qr = qs + hc * 128;
    float acc = 0.f;
#pragma unroll 8
    for (int u = 0; u < 32; u++) {
      uint32_t b4 = kr[u];
      acc += __builtin_amdgcn_cvt_f32_fp8(b4, 0) * qr[u * 4 + 0];
      acc += __builtin_amdgcn_cvt_f32_fp8(b4, 1) * qr[u * 4 + 1];
      acc += __builtin_amdgcn_cvt_f32_fp8(b4, 2) * qr[u * 4 + 2];
      acc += __builtin_amdgcn_cvt_f32_fp8(b4, 3) * qr[u * 4 + 3];
    }
    ls[tid] = acc;
  }
  __syncthreads();
  if (tid < 128) ls[tid] += ls[tid + 128];
  __syncthreads();

  float zzv;
  {
    const unsigned char* kc = ksb + (tid & ~3);
    int sh = (tid & 3) * 8;
    float acc = 0.f;
#pragma unroll 8
    for (int kk = 0; kk < 128; kk++) {
      uint32_t d = *(const uint32_t*)(kc + kk * 264);
      acc += ls[kk] * __builtin_amdgcn_cvt_f32_fp8((int)(d >> sh), 0);
    }
    zzv = acc;
  }
  __syncthreads();
  qs[tid] = zzv;
  __syncthreads();

  {
    int a = tid >> 4, e = tid & 15;
    const bf16* aw = actor_w + (size_t)a * 256 + e * 16;
    const float* zr = qs + e * 16;
    float acc = 0.f;
#pragma unroll
    for (int hh = 0; hh < 16; hh++) acc += (float)aw[hh] * zr[hh];
    sA[tid] = acc;
  }
  __syncthreads();
  if (tid < 16) {
    float lg = (float)actor_b[tid];
#pragma unroll
    for (int e = 0; e < 16; e++) lg += sA[tid * 16 + e];
    float mx = lg;
#pragma unroll
    for (int m = 8; m > 0; m >>= 1) mx = fmaxf(mx, __shfl_xor(mx, m, 16));
    float ex = __expf(lg - mx);
    float sm = ex;
#pragma unroll
    for (int m = 8; m > 0; m >>= 1) sm += __shfl_xor(sm, m, 16);
    al[tid] = ex / sm;
  }
  __syncthreads();

  if (tid < 16) {
    size_t off = (size_t)(t * 64 + n) * 339 + 259 + tid;
    if (flags[1]) ((float*)out_raw)[off] = al[tid];
    else ((bf16*)out_raw)[off] = (bf16)al[tid];
  }
}

// =====================================================================
extern "C" void kernel_launch(void* const* d_in, const int* in_sizes, int n_in,
                              void* d_out, int out_size, void* d_ws, size_t ws_size,
                              hipStream_t stream) {
  (void)in_sizes; (void)n_in; (void)out_size; (void)ws_size;
  const void* condition = d_in[0];
  const int* lines      = (const int*)d_in[1];
  const int* a_idx      = (const int*)d_in[2];
  const int* p_idx      = (const int*)d_in[3];

  char* ws = (char*)d_ws;
  bf16* xi            = (bf16*)(ws + XI_OFF);
  float* qs_ws        = (float*)(ws + QS_OFF);
  unsigned char* K1c  = (unsigned char*)(ws + K1_OFF);
  float* gi           = (float*)(ws + GI_OFF);
  float* hdec         = (float*)(ws + HD_OFF);
  int* slot_map       = (int*)(ws + SLOT_OFF);
  int* flags          = (int*)(ws + FLG_OFF);
  int* wl             = (int*)(ws + WL_OFF);
  bf16* cw            = (bf16*)(ws + CW_OFF);
  unsigned char* wh8  = (unsigned char*)(ws + WH8_OFF);

  static const int src_idx[26] = {4, 5, 6, 7, 8, 9, 10, 11, 12, 13, 14, 15, 16,
                                  17, 18, 19, 20, 21, 22, 23, 24, 25, 26, 27, 28, 29};
  static const int offs[26] = {o_embed, o_aemb, o_wi_f, o_wh_f, o_bi_f, o_bh_f,
                               o_wi_b, o_wh_b, o_bi_b, o_bh_b, o_f_w1, o_f_b1,
                               o_f_w2, o_f_b2, o_cell_wi, o_cell_wh, o_cell_bi,
                               o_cell_bh, o_critic_w, o_critic_b, o_pointer_w,
                               o_pointer_b, o_actor_w, o_actor_b, o_query_w, o_query_b};
  static const int cnts[26] = {32768, 4096, 196608, 196608, 768, 768,
                               196608, 196608, 768, 768, 81920, 256,
                               65536, 256, 196608, 196608, 768,
                               768, 256, 1, 16384, 64, 4096, 16, 65536, 256};
  PrepArgs pa;
  for (int i = 0; i < 26; i++) {
    pa.src[i] = d_in[src_idx[i]];
    pa.off[i] = offs[i];
    pa.cnt[i] = cnts[i];
  }

  k_prep<<<PREP_WGS + 1, 256, 0, stream>>>(pa, (const uint32_t*)condition,
                                           (const uint32_t*)d_in[4], d_in[7], d_in[11],
                                           p_idx, flags, cw, wh8, slot_map, wl);
  k_xi_gi<<<320, 256, 0, stream>>>(lines, cw, condition, flags, a_idx, xi, gi);
  k_main<<<516, 1024, 0, stream>>>(cw, wh8, xi, slot_map, wl, gi, K1c, hdec);
  k_heads<<<64, 256, 0, stream>>>(hdec, flags, a_idx, p_idx, cw, qs_ws, d_out);
  k_attn<<<2048, 256, 0, stream>>>(qs_ws, K1c, slot_map, flags, p_idx, cw, d_out);
}